// Round 4
// baseline (547.376 us; speedup 1.0000x reference)
//
#include <hip/hip_runtime.h>
#include <hip/hip_bf16.h>

#define N_NODES 50000
#define N_EDGES 800000
#define FDIM    128
#define HEADS   8
#define HID     16
#define NCLS    10
#define CLSP    16    // padded cls row (64B aligned)
#define SCB     512   // scan block size
#define NPART   8     // XCD partitions for CSR scatter/count
#define PSZ     6250  // N_NODES / NPART
#define GROWS   64    // gemm rows per block (layer 0)
#define GR      16    // fused agg+gemm rows per block (layers 1-4); 50000/16=3125 exact
#define NBIN    512   // degree histogram bins

typedef unsigned short u16;
typedef __attribute__((ext_vector_type(8))) short bf16x8;
typedef __attribute__((ext_vector_type(4))) float f32x4;

__device__ __forceinline__ float bf2f(u16 u) {
    union { unsigned int i; float f; } c; c.i = ((unsigned int)u) << 16; return c.f;
}
__device__ __forceinline__ float bf2f_hi(unsigned int u) {
    union { unsigned int i; float f; } c; c.i = u & 0xffff0000u; return c.f;
}
__device__ __forceinline__ float bf2f_lo(unsigned int u) {
    union { unsigned int i; float f; } c; c.i = u << 16; return c.f;
}
__device__ __forceinline__ u16 f2bf(float f) {
    union { float f; unsigned int i; } c; c.f = f;
    unsigned int r = c.i + 0x7FFFu + ((c.i >> 16) & 1u);
    return (u16)(r >> 16);
}
__device__ __forceinline__ unsigned int pk2(float a, float b) {
    return (unsigned int)f2bf(a) | ((unsigned int)f2bf(b) << 16);
}
__device__ __forceinline__ float4 bf2f4(ushort4 u) {
    return make_float4(bf2f(u.x), bf2f(u.y), bf2f(u.z), bf2f(u.w));
}
__device__ __forceinline__ float4 ld4f(const u16* p)  { return bf2f4(*(const ushort4*)p); }
__device__ __forceinline__ void   st4(u16* p, float4 v) {
    ushort4 u; u.x = f2bf(v.x); u.y = f2bf(v.y); u.z = f2bf(v.z); u.w = f2bf(v.w);
    *(ushort4*)p = u;
}

// external-input decode (dtype resolved at runtime via flag)
__device__ __forceinline__ float ldin(const void* p, int i, bool isf32) {
    return isf32 ? ((const float*)p)[i] : bf2f(((const u16*)p)[i]);
}
__device__ __forceinline__ float4 ldin4(const void* p, int i4, bool isf32) {
    if (isf32) return ((const float4*)p)[i4];
    return bf2f4(((const ushort4*)p)[i4]);
}

// ---------------- dtype detection (W0 scan) + deg/hist zeroing (merged grid) ----------------
__global__ void detect_and_zero(const u16* __restrict__ w, int n, int* __restrict__ flag,
                                int* __restrict__ deg, int* __restrict__ hist) {
    if (blockIdx.x != 0) {
        int i = (blockIdx.x - 1) * 256 + threadIdx.x;
        if (i < N_NODES) deg[i] = 0;
        if (i < NBIN) hist[i] = 0;
        return;
    }
    __shared__ int s_huge, s_zero;
    if (threadIdx.x == 0) { s_huge = 0; s_zero = 0; }
    __syncthreads();
    int huge = 0, zero = 0;
    for (int i = threadIdx.x * 8; i < n; i += 256 * 8) {
        ushort4 a = *(const ushort4*)(w + i);
        ushort4 b = *(const ushort4*)(w + i + 4);
        u16 vals[8] = { a.x, a.y, a.z, a.w, b.x, b.y, b.z, b.w };
        #pragma unroll
        for (int k = 0; k < 8; k++) {
            float v = bf2f(vals[k]);
            if (fabsf(v) > 1e9f || v != v) huge++;
            if (vals[k] == 0) zero++;
        }
    }
    atomicAdd(&s_huge, huge);
    atomicAdd(&s_zero, zero);
    __syncthreads();
    if (threadIdx.x == 0)
        *flag = (s_huge > 0 || s_zero > n / 4) ? 1 : 0;
}

// ---------------- W transpose to bf16 (Wt[n][k]) for MFMA B-frags ----------------
__global__ void prep_wt(const void* __restrict__ W0, const void* __restrict__ W1,
                        const void* __restrict__ W2, const void* __restrict__ W3,
                        u16* __restrict__ Wt, const int* __restrict__ dflag) {
    const bool isf32 = (*dflag != 0);
    int l = blockIdx.y;
    const void* W = (l == 0) ? W0 : (l == 1) ? W1 : (l == 2) ? W2 : W3;
    int i = blockIdx.x * 256 + threadIdx.x;
    if (i >= FDIM * FDIM) return;
    int n = i >> 7, k = i & 127;
    Wt[l * FDIM * FDIM + n * FDIM + k] = f2bf(ldin(W, k * FDIM + n, isf32));
}

// ---------------- CSR build + degree histogram ----------------

__global__ void __launch_bounds__(SCB)
deg_bsum(const int* __restrict__ deg, int* __restrict__ bsum, int* __restrict__ hist) {
    __shared__ int lh[NBIN];
    lh[threadIdx.x] = 0;
    __syncthreads();
    int i = blockIdx.x * SCB + threadIdx.x;
    int v = (i < N_NODES) ? deg[i] : 0;
    if (i < N_NODES) atomicAdd(&lh[v > NBIN - 1 ? NBIN - 1 : v], 1);
    int s = v;
    for (int off = 32; off; off >>= 1) s += __shfl_down(s, off, 64);
    __shared__ int wsum[SCB / 64];
    int wv = threadIdx.x >> 6, ln = threadIdx.x & 63;
    if (ln == 0) wsum[wv] = s;
    __syncthreads();
    if (threadIdx.x == 0) {
        int t = 0;
        #pragma unroll
        for (int k = 0; k < SCB / 64; k++) t += wsum[k];
        bsum[blockIdx.x] = t;
    }
    if (lh[threadIdx.x]) atomicAdd(&hist[threadIdx.x], lh[threadIdx.x]);
}

// suffix-exclusive scan of hist (descending-degree bases): binCur[d] = #{nodes deg > d}
__global__ void __launch_bounds__(NBIN)
scan_bins(const int* __restrict__ hist, int* __restrict__ binCur) {
    __shared__ int sd[NBIN];
    int tid = threadIdx.x;
    int v = hist[NBIN - 1 - tid];
    sd[tid] = v;
    __syncthreads();
    for (int off = 1; off < NBIN; off <<= 1) {
        int t = (tid >= off) ? sd[tid - off] : 0;
        __syncthreads();
        sd[tid] += t;
        __syncthreads();
    }
    binCur[NBIN - 1 - tid] = sd[tid] - v;   // exclusive suffix sum
}

// block scan of deg -> row_ptr/cursor; plus degree-bucket scatter -> perm (LPT order)
__global__ void __launch_bounds__(SCB)
deg_scan2(const int* __restrict__ deg, const int* __restrict__ bsum,
          int* __restrict__ row_ptr, int* __restrict__ cursor,
          int* __restrict__ binCur, int* __restrict__ perm) {
    __shared__ int sd[SCB];
    __shared__ int spfx;
    int tid = threadIdx.x;
    int i = blockIdx.x * SCB + tid;
    int v = (i < N_NODES) ? deg[i] : 0;
    sd[tid] = v;
    if (tid < 64) {
        int p = 0;
        if (tid < (int)blockIdx.x) p = bsum[tid];
        if (64 + tid < (int)blockIdx.x) p += bsum[64 + tid];
        for (int off = 32; off; off >>= 1) p += __shfl_down(p, off, 64);
        if (tid == 0) spfx = p;
    }
    __syncthreads();
    for (int off = 1; off < SCB; off <<= 1) {
        int t = (tid >= off) ? sd[tid - off] : 0;
        __syncthreads();
        sd[tid] += t;
        __syncthreads();
    }
    if (i < N_NODES) {
        int ex = sd[tid] - v + spfx;
        row_ptr[i] = ex;
        cursor[i] = ex;
        int d = v > NBIN - 1 ? NBIN - 1 : v;
        int pos = atomicAdd(&binCur[d], 1);
        perm[pos] = i;
    }
    if (blockIdx.x == 0 && tid == 0) row_ptr[N_NODES] = N_EDGES;
}

// XCD-partitioned scatter into u16 srcs (node ids < 65536).
__global__ void __launch_bounds__(256)
fill_csr_x(const int* __restrict__ src, const int* __restrict__ dst,
           int* __restrict__ cursor, u16* __restrict__ srcs, int blocksPerPart) {
    int part = blockIdx.x & (NPART - 1);
    int sub  = blockIdx.x >> 3;
    int lo = part * PSZ, hi = lo + PSZ;
    int stride = blocksPerPart * 256;
    for (int i = sub * 256 + threadIdx.x; i < N_EDGES; i += stride) {
        int d = __builtin_nontemporal_load(&dst[i]);
        if (d >= lo && d < hi) {
            int pos = atomicAdd(&cursor[d], 1);
            srcs[pos] = (u16)__builtin_nontemporal_load(&src[i]);
        }
    }
}

// ---------------- merged: layer-0 MFMA GEMM (+el/er)  ||  CSR degree count ----------------

__global__ void __launch_bounds__(256)
gemm0_count(const void* __restrict__ A, const u16* __restrict__ Wt,
            const void* __restrict__ alw, const void* __restrict__ arw,
            u16* __restrict__ C, float* __restrict__ el, float* __restrict__ er,
            const int* __restrict__ dflag,
            const int* __restrict__ dst, int* __restrict__ deg,
            int gemmBlocks, int blocksPerPart) {
    __shared__ __align__(16) char smem[GROWS * 132 * 4];  // Ct fp32 aliases As bf16
    if ((int)blockIdx.x >= gemmBlocks) {
        int b = blockIdx.x - gemmBlocks;
        int part = b & (NPART - 1);
        int sub  = b >> 3;
        int lo = part * PSZ, hi = lo + PSZ;
        int stride = blocksPerPart * 256;
        for (int i = sub * 256 + threadIdx.x; i < N_EDGES; i += stride) {
            int d = __builtin_nontemporal_load(&dst[i]);
            if (d >= lo && d < hi) atomicAdd(&deg[d], 1);
        }
        return;
    }
    u16   (*As)[136] = (u16(*)[136])smem;
    float (*Ct)[132] = (float(*)[132])smem;
    __shared__ u16 alv[128], arv[128];
    const bool isf32 = (*dflag != 0);
    int tid = threadIdx.x;
    if (tid < 128) {
        alv[tid] = f2bf(ldin(alw, tid, isf32));
        arv[tid] = f2bf(ldin(arw, tid, isf32));
    }
    int rowBase = blockIdx.x * GROWS;
    for (int t = tid; t < GROWS * 32; t += 256) {
        int r = t >> 5, q = t & 31;
        int n = rowBase + r;
        float4 v = make_float4(0.f, 0.f, 0.f, 0.f);
        if (n < N_NODES) v = ldin4(A, n * 32 + q, isf32);
        ushort4 u; u.x = f2bf(v.x); u.y = f2bf(v.y); u.z = f2bf(v.z); u.w = f2bf(v.w);
        *(ushort4*)&As[r][q * 4] = u;
    }
    int wv = tid >> 6, ln = tid & 63;
    int ln15 = ln & 15, quad = ln >> 4;
    bf16x8 bfr[2][4];
    #pragma unroll
    for (int c = 0; c < 2; c++)
        #pragma unroll
        for (int kk = 0; kk < 4; kk++)
            bfr[c][kk] = *(const bf16x8*)(Wt + (wv * 32 + c * 16 + ln15) * FDIM + kk * 32 + quad * 8);
    __syncthreads();
    f32x4 acc[4][2] = {};
    #pragma unroll
    for (int kk = 0; kk < 4; kk++) {
        #pragma unroll
        for (int rt = 0; rt < 4; rt++) {
            bf16x8 a = *(const bf16x8*)&As[rt * 16 + ln15][kk * 32 + quad * 8];
            acc[rt][0] = __builtin_amdgcn_mfma_f32_16x16x32_bf16(a, bfr[0][kk], acc[rt][0], 0, 0, 0);
            acc[rt][1] = __builtin_amdgcn_mfma_f32_16x16x32_bf16(a, bfr[1][kk], acc[rt][1], 0, 0, 0);
        }
    }
    __syncthreads();
    #pragma unroll
    for (int rt = 0; rt < 4; rt++)
        #pragma unroll
        for (int c = 0; c < 2; c++)
            #pragma unroll
            for (int p = 0; p < 4; p++)
                Ct[rt * 16 + quad * 4 + p][wv * 32 + c * 16 + ln15] = acc[rt][c][p];
    __syncthreads();
    int jc = (tid & 31) * 4, r0 = (tid >> 5) * 8;
    #pragma unroll
    for (int r = 0; r < 8; r++) {
        int n = rowBase + r0 + r;
        if (n < N_NODES)
            st4(C + (size_t)n * FDIM + jc, *(const float4*)&Ct[r0 + r][jc]);
    }
    int head = tid & 7;
    #pragma unroll
    for (int rr = 0; rr < 2; rr++) {
        int row = (tid >> 3) + rr * 32;
        int n2 = rowBase + row;
        if (n2 < N_NODES) {
            float sl = 0.f, sr = 0.f;
            #pragma unroll
            for (int k = 0; k < HID; k++) {
                float v = Ct[row][head * HID + k];
                sl += v * bf2f(alv[head * HID + k]);
                sr += v * bf2f(arv[head * HID + k]);
            }
            el[n2 * HEADS + head] = sl;
            er[n2 * HEADS + head] = sr;
        }
    }
}

// ---------------- shared agg phase: 16 perm-ordered nodes/block -> bf16 rows in LDS ----------------
// Degree-sorted perm: the 4 nodes of a wave have (near-)equal degree -> no divergence.
// Wave layout: 4 nodes (sub=ln>>4), 4 edge slots (g=(ln>>2)&3), 2 heads/lane (q2=ln&3).
// srcs AND el prefetched one step ahead. No tail checks (N_NODES % GR == 0).

__device__ __forceinline__ void agg_rows(
    const u16* __restrict__ featP, const float* __restrict__ elP,
    const float* __restrict__ erP, const int* __restrict__ row_ptr,
    const u16* __restrict__ srcs, const int* __restrict__ perm,
    int rowBase, int tid, u16 (*As)[136]) {
    int wv = tid >> 6, ln = tid & 63;
    int sub = ln >> 4;            // node within wave (0..3)
    int g   = (ln >> 2) & 3;      // edge slot (0..3)
    int q2  = ln & 3;             // head pair
    int k15 = ln & 15;
    int rp = 0;
    if (k15 < 8) {
        int pidx = perm[rowBase + wv * 4 + (k15 & 3)];
        rp = row_ptr[pidx + (k15 >> 2)];
    }
    int r = wv * 4 + sub;
    int pn = perm[rowBase + r];   // this sub's node (original id)
    int beg = __shfl(rp, sub, 64);
    int end = __shfl(rp, sub + 4, 64);
    float2 erv = *(const float2*)&erP[pn * HEADS + q2 * 2];
    float ss0 = 0.f, ss1 = 0.f;
    float acc[32] = {};
    // prefetch first src + el (OOB-safe)
    int idx0 = beg + g;
    int sN = srcs[(idx0 < end) ? idx0 : ((beg < end) ? beg : 0)];
    float2 elN_ = *(const float2*)&elP[sN * HEADS + q2 * 2];
    for (int i = beg; i < end; i += 4) {
        bool v = (i + g) < end;
        int s_cur = sN;
        float2 elv = elN_;
        int nidx = i + 4 + g;
        sN = srcs[(nidx < end) ? nidx : beg];              // prefetch next src
        elN_ = *(const float2*)&elP[sN * HEADS + q2 * 2];  // prefetch next el
        float e0 = elv.x + erv.x;
        float e1 = elv.y + erv.y;
        e0 = fmaxf(e0, 0.2f * e0);
        e1 = fmaxf(e1, 0.2f * e1);
        float x0 = v ? __expf(fminf(e0, 80.f)) : 0.f;
        float x1 = v ? __expf(fminf(e1, 80.f)) : 0.f;
        const u16* fr = featP + (size_t)s_cur * FDIM + q2 * 32;
        uint4 u0 = *(const uint4*)fr;
        uint4 u1 = *(const uint4*)(fr + 8);
        uint4 u2 = *(const uint4*)(fr + 16);
        uint4 u3 = *(const uint4*)(fr + 24);
        ss0 += x0; ss1 += x1;
        acc[0]  = fmaf(x0, bf2f_lo(u0.x), acc[0]);  acc[1]  = fmaf(x0, bf2f_hi(u0.x), acc[1]);
        acc[2]  = fmaf(x0, bf2f_lo(u0.y), acc[2]);  acc[3]  = fmaf(x0, bf2f_hi(u0.y), acc[3]);
        acc[4]  = fmaf(x0, bf2f_lo(u0.z), acc[4]);  acc[5]  = fmaf(x0, bf2f_hi(u0.z), acc[5]);
        acc[6]  = fmaf(x0, bf2f_lo(u0.w), acc[6]);  acc[7]  = fmaf(x0, bf2f_hi(u0.w), acc[7]);
        acc[8]  = fmaf(x0, bf2f_lo(u1.x), acc[8]);  acc[9]  = fmaf(x0, bf2f_hi(u1.x), acc[9]);
        acc[10] = fmaf(x0, bf2f_lo(u1.y), acc[10]); acc[11] = fmaf(x0, bf2f_hi(u1.y), acc[11]);
        acc[12] = fmaf(x0, bf2f_lo(u1.z), acc[12]); acc[13] = fmaf(x0, bf2f_hi(u1.z), acc[13]);
        acc[14] = fmaf(x0, bf2f_lo(u1.w), acc[14]); acc[15] = fmaf(x0, bf2f_hi(u1.w), acc[15]);
        acc[16] = fmaf(x1, bf2f_lo(u2.x), acc[16]); acc[17] = fmaf(x1, bf2f_hi(u2.x), acc[17]);
        acc[18] = fmaf(x1, bf2f_lo(u2.y), acc[18]); acc[19] = fmaf(x1, bf2f_hi(u2.y), acc[19]);
        acc[20] = fmaf(x1, bf2f_lo(u2.z), acc[20]); acc[21] = fmaf(x1, bf2f_hi(u2.z), acc[21]);
        acc[22] = fmaf(x1, bf2f_lo(u2.w), acc[22]); acc[23] = fmaf(x1, bf2f_hi(u2.w), acc[23]);
        acc[24] = fmaf(x1, bf2f_lo(u3.x), acc[24]); acc[25] = fmaf(x1, bf2f_hi(u3.x), acc[25]);
        acc[26] = fmaf(x1, bf2f_lo(u3.y), acc[26]); acc[27] = fmaf(x1, bf2f_hi(u3.y), acc[27]);
        acc[28] = fmaf(x1, bf2f_lo(u3.z), acc[28]); acc[29] = fmaf(x1, bf2f_hi(u3.z), acc[29]);
        acc[30] = fmaf(x1, bf2f_lo(u3.w), acc[30]); acc[31] = fmaf(x1, bf2f_hi(u3.w), acc[31]);
    }
    ss0 += __shfl_xor(ss0, 4, 64);
    ss0 += __shfl_xor(ss0, 8, 64);
    ss1 += __shfl_xor(ss1, 4, 64);
    ss1 += __shfl_xor(ss1, 8, 64);
    #pragma unroll
    for (int k = 0; k < 32; k++) {
        acc[k] += __shfl_xor(acc[k], 4, 64);
        acc[k] += __shfl_xor(acc[k], 8, 64);
    }
    if (g == 0) {
        float inv0 = (end > beg) ? 1.f / ss0 : 0.f;
        float inv1 = (end > beg) ? 1.f / ss1 : 0.f;
        float rr[32];
        #pragma unroll
        for (int k = 0; k < 32; k++) {
            float t = acc[k] * ((k < 16) ? inv0 : inv1);
            rr[k] = (t > 0.f) ? t : (__expf(t) - 1.f);   // ELU
        }
        uint4 o0, o1, o2, o3;
        o0.x = pk2(rr[0],  rr[1]);  o0.y = pk2(rr[2],  rr[3]);
        o0.z = pk2(rr[4],  rr[5]);  o0.w = pk2(rr[6],  rr[7]);
        o1.x = pk2(rr[8],  rr[9]);  o1.y = pk2(rr[10], rr[11]);
        o1.z = pk2(rr[12], rr[13]); o1.w = pk2(rr[14], rr[15]);
        o2.x = pk2(rr[16], rr[17]); o2.y = pk2(rr[18], rr[19]);
        o2.z = pk2(rr[20], rr[21]); o2.w = pk2(rr[22], rr[23]);
        o3.x = pk2(rr[24], rr[25]); o3.y = pk2(rr[26], rr[27]);
        o3.z = pk2(rr[28], rr[29]); o3.w = pk2(rr[30], rr[31]);
        u16* dp = &As[r][q2 * 32];
        *(uint4*)dp        = o0;
        *(uint4*)(dp + 8)  = o1;
        *(uint4*)(dp + 16) = o2;
        *(uint4*)(dp + 24) = o3;
    }
}

// ---------------- fused agg (layer l-1, ELU) + MFMA GEMM (layer l) ----------------

__global__ void __launch_bounds__(256)
fused_agg_gemm(const u16* __restrict__ featP, const float* __restrict__ elP,
               const float* __restrict__ erP, const int* __restrict__ row_ptr,
               const u16* __restrict__ srcs, const int* __restrict__ perm,
               const u16* __restrict__ Wt,
               const void* __restrict__ alw, const void* __restrict__ arw,
               u16* __restrict__ featN, float* __restrict__ elN, float* __restrict__ erN,
               const int* __restrict__ dflag) {
    __shared__ __align__(16) char smem[GR * 132 * 4];   // Ct f32 (8448B) aliases As bf16 (4352B)
    u16   (*As)[136] = (u16(*)[136])smem;
    float (*Ct)[132] = (float(*)[132])smem;
    __shared__ u16 alv[128], arv[128];
    const bool isf32 = (*dflag != 0);
    int tid = threadIdx.x;
    if (tid < 128) {
        alv[tid] = f2bf(ldin(alw, tid, isf32));
        arv[tid] = f2bf(ldin(arw, tid, isf32));
    }
    int rowBase = blockIdx.x * GR;
    agg_rows(featP, elP, erP, row_ptr, srcs, perm, rowBase, tid, As);
    int wv = tid >> 6, ln = tid & 63;
    int ln15 = ln & 15, quad = ln >> 4;
    bf16x8 bfr[2][4];
    #pragma unroll
    for (int c = 0; c < 2; c++)
        #pragma unroll
        for (int kk = 0; kk < 4; kk++)
            bfr[c][kk] = *(const bf16x8*)(Wt + (wv * 32 + c * 16 + ln15) * FDIM + kk * 32 + quad * 8);
    __syncthreads();
    // ---- GEMM phase (16 rows; wave wv -> cols wv*32..+31) ----
    f32x4 acc2[2] = {};
    #pragma unroll
    for (int kk = 0; kk < 4; kk++) {
        bf16x8 a = *(const bf16x8*)&As[ln15][kk * 32 + quad * 8];
        acc2[0] = __builtin_amdgcn_mfma_f32_16x16x32_bf16(a, bfr[0][kk], acc2[0], 0, 0, 0);
        acc2[1] = __builtin_amdgcn_mfma_f32_16x16x32_bf16(a, bfr[1][kk], acc2[1], 0, 0, 0);
    }
    __syncthreads();   // As reads done; smem becomes Ct
    #pragma unroll
    for (int c = 0; c < 2; c++)
        #pragma unroll
        for (int p = 0; p < 4; p++)
            Ct[quad * 4 + p][wv * 32 + c * 16 + ln15] = acc2[c][p];
    __syncthreads();
    // bf16 feat store: thread stores 2 rows x 4 cols (perm scatter; row-contiguous)
    int jc = (tid & 31) * 4, r0s = (tid >> 5) * 2;
    #pragma unroll
    for (int r2 = 0; r2 < 2; r2++) {
        int n = perm[rowBase + r0s + r2];
        st4(featN + (size_t)n * FDIM + jc, *(const float4*)&Ct[r0s + r2][jc]);
    }
    // fused el/er: 16 rows x 8 heads = 128 items
    if (tid < 128) {
        int head = tid & 7, row2 = tid >> 3;
        int n2 = perm[rowBase + row2];
        float sl = 0.f, sr = 0.f;
        #pragma unroll
        for (int k = 0; k < HID; k++) {
            float v = Ct[row2][head * HID + k];
            sl += v * bf2f(alv[head * HID + k]);
            sr += v * bf2f(arv[head * HID + k]);
        }
        elN[n2 * HEADS + head] = sl;
        erN[n2 * HEADS + head] = sr;
    }
}

// ---------------- fused agg (layer 3, ELU) + classifier GEMM (layer 4) + el/er ----------------

__global__ void __launch_bounds__(256)
fused_agg_cls(const u16* __restrict__ featP, const float* __restrict__ elP,
              const float* __restrict__ erP, const int* __restrict__ row_ptr,
              const u16* __restrict__ srcs, const int* __restrict__ perm,
              const void* __restrict__ W4,
              const void* __restrict__ alw, const void* __restrict__ arw,
              float* __restrict__ cls, float* __restrict__ elN, float* __restrict__ erN,
              const int* __restrict__ dflag) {
    __shared__ __align__(16) u16 As[GR][136];
    __shared__ float Wl[128][16];
    const bool isf32 = (*dflag != 0);
    int tid = threadIdx.x;
    for (int t = tid; t < 128 * 16; t += 256) {
        int k = t >> 4, c = t & 15;
        Wl[k][c] = (c < NCLS) ? ldin(W4, k * NCLS + c, isf32) : 0.f;
    }
    int rowBase = blockIdx.x * GR;
    agg_rows(featP, elP, erP, row_ptr, srcs, perm, rowBase, tid, As);
    __syncthreads();
    // classifier: 16 rows x 16 cols, 1 output/thread
    int c = tid & 15;
    int row = tid >> 4;
    int n = perm[rowBase + row];
    float alc = (c < NCLS) ? ldin(alw, c, isf32) : 0.f;
    float arc = (c < NCLS) ? ldin(arw, c, isf32) : 0.f;
    float acc = 0.f;
    #pragma unroll
    for (int qq = 0; qq < 32; qq++) {
        float4 v = ld4f(&As[row][qq * 4]);
        acc += v.x * Wl[qq * 4 + 0][c] + v.y * Wl[qq * 4 + 1][c] +
               v.z * Wl[qq * 4 + 2][c] + v.w * Wl[qq * 4 + 3][c];
    }
    cls[n * CLSP + c] = acc;
    float sl = acc * alc, sr = acc * arc;
    #pragma unroll
    for (int off = 8; off >= 1; off >>= 1) {
        sl += __shfl_xor(sl, off, 64);
        sr += __shfl_xor(sr, off, 64);
    }
    if (c == 0) { elN[n] = sl; erN[n] = sr; }
}

// ---------------- final aggregation: 4 nodes per wave (16 lanes each) ----------------

__global__ void __launch_bounds__(256)
agg4(const float* __restrict__ feat, const float* __restrict__ el,
     const float* __restrict__ er, const int* __restrict__ row_ptr,
     const u16* __restrict__ srcs, void* __restrict__ out,
     const int* __restrict__ dflag) {
    const bool isf32 = (*dflag != 0);
    int wid = (blockIdx.x * 256 + threadIdx.x) >> 6;
    int lane = threadIdx.x & 63;
    int g = lane >> 4, t = lane & 15;
    int node = wid * 4 + g;
    bool vn = node < N_NODES;
    int nn = vn ? node : 0;
    int beg = row_ptr[nn];
    int end = vn ? row_ptr[nn + 1] : beg;
    float ern = er[nn];
    int deg = end - beg;
    int mx = deg;
    mx = max(mx, __shfl_xor(mx, 16, 64));
    mx = max(mx, __shfl_xor(mx, 32, 64));
    float ssA = 0.f, ssB = 0.f, aA = 0.f, aB = 0.f;
    int k = 0;
    for (; k + 1 < mx; k += 2) {
        int i0 = beg + k, i1 = i0 + 1;
        bool v0 = i0 < end, v1 = i1 < end;
        int s0 = srcs[v0 ? i0 : beg];
        int s1 = srcs[v1 ? i1 : beg];
        float e0 = el[s0] + ern;
        float e1 = el[s1] + ern;
        float f0 = feat[s0 * CLSP + t];
        float f1 = feat[s1 * CLSP + t];
        e0 = fmaxf(e0, 0.2f * e0); e1 = fmaxf(e1, 0.2f * e1);
        float x0 = v0 ? __expf(fminf(e0, 80.f)) : 0.f;
        float x1 = v1 ? __expf(fminf(e1, 80.f)) : 0.f;
        ssA += x0; ssB += x1;
        aA = fmaf(x0, f0, aA);
        aB = fmaf(x1, f1, aB);
    }
    if (k < mx) {
        int i0 = beg + k;
        bool v0 = i0 < end;
        int s0 = srcs[v0 ? i0 : beg];
        float e0 = el[s0] + ern;
        e0 = fmaxf(e0, 0.2f * e0);
        float x0 = v0 ? __expf(fminf(e0, 80.f)) : 0.f;
        ssA += x0;
        aA = fmaf(x0, feat[s0 * CLSP + t], aA);
    }
    float ss = ssA + ssB, a = aA + aB;
    if (vn && t < NCLS) {
        float r = (deg > 0) ? a / ss : 0.f;
        if (isf32) ((float*)out)[node * NCLS + t] = r;
        else       ((u16*)out)[node * NCLS + t] = f2bf(r);
    }
}

// ---------------- launch ----------------

extern "C" void kernel_launch(void* const* d_in, const int* in_sizes, int n_in,
                              void* d_out, int out_size, void* d_ws, size_t ws_size,
                              hipStream_t stream) {
    const void* h_in = d_in[0];
    const int* src   = (const int*)d_in[1];
    const int* dst   = (const int*)d_in[2];
    const void *W[5], *al[5], *ar[5];
    for (int l = 0; l < 5; l++) {
        W[l]  = d_in[3 + 3 * l];
        al[l] = d_in[4 + 3 * l];
        ar[l] = d_in[5 + 3 * l];
    }

    char* ws = (char*)d_ws;
    size_t off = 0;
    auto alloc = [&](size_t bytes) {
        void* p = ws + off;
        off = (off + bytes + 255) & ~(size_t)255;
        return p;
    };
    int* dflag   = (int*)alloc(4);
    u16* feat0   = (u16*)alloc((size_t)N_NODES * FDIM * sizeof(u16)); // ping
    u16* feat1   = (u16*)alloc((size_t)N_NODES * FDIM * sizeof(u16)); // pong
    u16* Wt      = (u16*)alloc(4ull * FDIM * FDIM * sizeof(u16));     // transposed bf16 weights
    float* el0   = (float*)alloc((size_t)N_NODES * HEADS * 4);
    float* er0   = (float*)alloc((size_t)N_NODES * HEADS * 4);
    float* el1   = (float*)alloc((size_t)N_NODES * HEADS * 4);
    float* er1   = (float*)alloc((size_t)N_NODES * HEADS * 4);
    float* cls   = (float*)alloc((size_t)N_NODES * CLSP * 4);
    int* deg     = (int*)alloc((size_t)N_NODES * 4);
    int* row_ptr = (int*)alloc((size_t)(N_NODES + 1) * 4);
    int* cursor  = (int*)alloc((size_t)N_NODES * 4);
    u16* srcs    = (u16*)alloc((size_t)N_EDGES * 2);
    int* bsum    = (int*)alloc(256 * 4);
    int* hist    = (int*)alloc(NBIN * 4);
    int* binCur  = (int*)alloc(NBIN * 4);
    int* perm    = (int*)alloc((size_t)N_NODES * 4);

    const int NB = (N_NODES + SCB - 1) / SCB;          // 98 scan blocks
    const int GB = (N_NODES + GROWS - 1) / GROWS;      // 782 gemm0 blocks
    const int CPP = 128;                               // count blocks per partition
    const int BPP = 256;                               // fill blocks per partition
    const int FB = N_NODES / GR;                       // 3125 fused blocks (exact)

    detect_and_zero<<<1 + (N_NODES + 255) / 256, 256, 0, stream>>>(
        (const u16*)W[0], FDIM * FDIM, dflag, deg, hist);
    prep_wt<<<dim3((FDIM * FDIM + 255) / 256, 4), 256, 0, stream>>>(
        W[0], W[1], W[2], W[3], Wt, dflag);

    // layer-0 GEMM overlapped with CSR degree count (independent)
    gemm0_count<<<GB + NPART * CPP, 256, 0, stream>>>(
        h_in, Wt, al[0], ar[0], feat0, el0, er0, dflag, dst, deg, GB, CPP);

    deg_bsum<<<NB, SCB, 0, stream>>>(deg, bsum, hist);
    scan_bins<<<1, NBIN, 0, stream>>>(hist, binCur);
    deg_scan2<<<NB, SCB, 0, stream>>>(deg, bsum, row_ptr, cursor, binCur, perm);
    fill_csr_x<<<NPART * BPP, 256, 0, stream>>>(src, dst, cursor, srcs, BPP);

    // layers 1-3: fused agg(l-1)+gemm(l), ping-pong buffers, degree-sorted node order
    fused_agg_gemm<<<FB, 256, 0, stream>>>(
        feat0, el0, er0, row_ptr, srcs, perm, Wt + 1 * FDIM * FDIM, al[1], ar[1],
        feat1, el1, er1, dflag);
    fused_agg_gemm<<<FB, 256, 0, stream>>>(
        feat1, el1, er1, row_ptr, srcs, perm, Wt + 2 * FDIM * FDIM, al[2], ar[2],
        feat0, el0, er0, dflag);
    fused_agg_gemm<<<FB, 256, 0, stream>>>(
        feat0, el0, er0, row_ptr, srcs, perm, Wt + 3 * FDIM * FDIM, al[3], ar[3],
        feat1, el1, er1, dflag);
    // layer-3 aggregation fused with classifier GEMM + layer-4 el/er
    fused_agg_cls<<<FB, 256, 0, stream>>>(
        feat1, el1, er1, row_ptr, srcs, perm, W[4], al[4], ar[4], cls, el0, er0, dflag);
    agg4<<<(N_NODES / 16 + 1), 256, 0, stream>>>(cls, el0, er0, row_ptr, srcs, d_out, dflag);
}

// Round 5
// 473.781 us; speedup vs baseline: 1.1553x; 1.1553x over previous
//
#include <hip/hip_runtime.h>
#include <hip/hip_bf16.h>

#define N_NODES 50000
#define N_EDGES 800000
#define FDIM    128
#define HEADS   8
#define HID     16
#define NCLS    10
#define CLSP    16    // padded cls row (64B aligned)
#define SCB     512   // scan block size
#define NPART   8     // XCD partitions for CSR scatter/count
#define PSZ     6250  // N_NODES / NPART
#define GROWS   64    // gemm rows per block
#define PS      ((size_t)N_NODES * 32)   // feat plane stride (u16 elems); plane = 3.2MB
#define NTILE   (N_NODES / 16)           // 3125 agg tiles (16 nodes each)

typedef unsigned short u16;
typedef __attribute__((ext_vector_type(8))) short bf16x8;
typedef __attribute__((ext_vector_type(4))) float f32x4;

__device__ __forceinline__ float bf2f(u16 u) {
    union { unsigned int i; float f; } c; c.i = ((unsigned int)u) << 16; return c.f;
}
__device__ __forceinline__ float bf2f_hi(unsigned int u) {
    union { unsigned int i; float f; } c; c.i = u & 0xffff0000u; return c.f;
}
__device__ __forceinline__ float bf2f_lo(unsigned int u) {
    union { unsigned int i; float f; } c; c.i = u << 16; return c.f;
}
__device__ __forceinline__ u16 f2bf(float f) {
    union { float f; unsigned int i; } c; c.f = f;
    unsigned int r = c.i + 0x7FFFu + ((c.i >> 16) & 1u);
    return (u16)(r >> 16);
}
__device__ __forceinline__ unsigned int pk2(float a, float b) {
    return (unsigned int)f2bf(a) | ((unsigned int)f2bf(b) << 16);
}
__device__ __forceinline__ float4 bf2f4(ushort4 u) {
    return make_float4(bf2f(u.x), bf2f(u.y), bf2f(u.z), bf2f(u.w));
}
__device__ __forceinline__ float4 ld4f(const u16* p)  { return bf2f4(*(const ushort4*)p); }
__device__ __forceinline__ void   st4(u16* p, float4 v) {
    ushort4 u; u.x = f2bf(v.x); u.y = f2bf(v.y); u.z = f2bf(v.z); u.w = f2bf(v.w);
    *(ushort4*)p = u;
}

// external-input decode (dtype resolved at runtime via flag)
__device__ __forceinline__ float ldin(const void* p, int i, bool isf32) {
    return isf32 ? ((const float*)p)[i] : bf2f(((const u16*)p)[i]);
}
__device__ __forceinline__ float4 ldin4(const void* p, int i4, bool isf32) {
    if (isf32) return ((const float4*)p)[i4];
    return bf2f4(((const ushort4*)p)[i4]);
}

// ---------------- dtype detection (W0 scan) + deg zeroing (merged grid) ----------------
__global__ void detect_and_zero(const u16* __restrict__ w, int n, int* __restrict__ flag,
                                int* __restrict__ deg) {
    if (blockIdx.x != 0) {
        int i = (blockIdx.x - 1) * 256 + threadIdx.x;
        if (i < N_NODES) deg[i] = 0;
        return;
    }
    __shared__ int s_huge, s_zero;
    if (threadIdx.x == 0) { s_huge = 0; s_zero = 0; }
    __syncthreads();
    int huge = 0, zero = 0;
    for (int i = threadIdx.x * 8; i < n; i += 256 * 8) {
        ushort4 a = *(const ushort4*)(w + i);
        ushort4 b = *(const ushort4*)(w + i + 4);
        u16 vals[8] = { a.x, a.y, a.z, a.w, b.x, b.y, b.z, b.w };
        #pragma unroll
        for (int k = 0; k < 8; k++) {
            float v = bf2f(vals[k]);
            if (fabsf(v) > 1e9f || v != v) huge++;
            if (vals[k] == 0) zero++;
        }
    }
    atomicAdd(&s_huge, huge);
    atomicAdd(&s_zero, zero);
    __syncthreads();
    if (threadIdx.x == 0)
        *flag = (s_huge > 0 || s_zero > n / 4) ? 1 : 0;
}

// ---------------- W transpose to bf16 (Wt[n][k]) for MFMA B-frags ----------------
__global__ void prep_wt(const void* __restrict__ W0, const void* __restrict__ W1,
                        const void* __restrict__ W2, const void* __restrict__ W3,
                        u16* __restrict__ Wt, const int* __restrict__ dflag) {
    const bool isf32 = (*dflag != 0);
    int l = blockIdx.y;
    const void* W = (l == 0) ? W0 : (l == 1) ? W1 : (l == 2) ? W2 : W3;
    int i = blockIdx.x * 256 + threadIdx.x;
    if (i >= FDIM * FDIM) return;
    int n = i >> 7, k = i & 127;
    Wt[l * FDIM * FDIM + n * FDIM + k] = f2bf(ldin(W, k * FDIM + n, isf32));
}

// ---------------- CSR build ----------------

__global__ void __launch_bounds__(SCB)
deg_bsum(const int* __restrict__ deg, int* __restrict__ bsum) {
    int i = blockIdx.x * SCB + threadIdx.x;
    int v = (i < N_NODES) ? deg[i] : 0;
    for (int off = 32; off; off >>= 1) v += __shfl_down(v, off, 64);
    __shared__ int wsum[SCB / 64];
    int wv = threadIdx.x >> 6, ln = threadIdx.x & 63;
    if (ln == 0) wsum[wv] = v;
    __syncthreads();
    if (threadIdx.x == 0) {
        int s = 0;
        #pragma unroll
        for (int k = 0; k < SCB / 64; k++) s += wsum[k];
        bsum[blockIdx.x] = s;
    }
}

// block scan of deg; each block sums bsum[0..blockIdx.x-1] itself (one wave)
__global__ void __launch_bounds__(SCB)
deg_scan2(const int* __restrict__ deg, const int* __restrict__ bsum,
          int* __restrict__ row_ptr, int* __restrict__ cursor) {
    __shared__ int sd[SCB];
    __shared__ int spfx;
    int tid = threadIdx.x;
    int i = blockIdx.x * SCB + tid;
    int v = (i < N_NODES) ? deg[i] : 0;
    sd[tid] = v;
    if (tid < 64) {
        int p = 0;
        if (tid < (int)blockIdx.x) p = bsum[tid];
        if (64 + tid < (int)blockIdx.x) p += bsum[64 + tid];
        for (int off = 32; off; off >>= 1) p += __shfl_down(p, off, 64);
        if (tid == 0) spfx = p;
    }
    __syncthreads();
    for (int off = 1; off < SCB; off <<= 1) {
        int t = (tid >= off) ? sd[tid - off] : 0;
        __syncthreads();
        sd[tid] += t;
        __syncthreads();
    }
    if (i < N_NODES) {
        int ex = sd[tid] - v + spfx;
        row_ptr[i] = ex;
        cursor[i] = ex;
    }
    if (blockIdx.x == 0 && tid == 0) row_ptr[N_NODES] = N_EDGES;
}

// XCD-partitioned scatter into u16 srcs (node ids < 65536).
__global__ void __launch_bounds__(256)
fill_csr_x(const int* __restrict__ src, const int* __restrict__ dst,
           int* __restrict__ cursor, u16* __restrict__ srcs, int blocksPerPart) {
    int part = blockIdx.x & (NPART - 1);
    int sub  = blockIdx.x >> 3;
    int lo = part * PSZ, hi = lo + PSZ;
    int stride = blocksPerPart * 256;
    for (int i = sub * 256 + threadIdx.x; i < N_EDGES; i += stride) {
        int d = __builtin_nontemporal_load(&dst[i]);
        if (d >= lo && d < hi) {
            int pos = atomicAdd(&cursor[d], 1);
            srcs[pos] = (u16)__builtin_nontemporal_load(&src[i]);
        }
    }
}

// ---------------- MFMA GEMM (+el/er); EXT=true also hosts CSR degree count blocks ----------------
// C planes layout: C[(col>>5)*PS + node*32 + (col&31)]  (4 planes x 3.2MB, one per head-pair).
// el written transposed: elT[head*N + node] (head-sliced gather in agg_h stays in one XCD's L2).

template<bool EXT>
__global__ void __launch_bounds__(256)
gemm_mfma(const void* __restrict__ A, const u16* __restrict__ Wt,
          const void* __restrict__ alw, const void* __restrict__ arw,
          u16* __restrict__ C, float* __restrict__ elT, float* __restrict__ er,
          const int* __restrict__ dflag,
          const int* __restrict__ dst, int* __restrict__ deg,
          int gemmBlocks, int blocksPerPart) {
    __shared__ __align__(16) char smem[GROWS * 132 * 4];  // Ct fp32 aliases As bf16
    if (EXT && (int)blockIdx.x >= gemmBlocks) {
        // ---- degree count branch (overlapped with layer-0 GEMM) ----
        int b = blockIdx.x - gemmBlocks;
        int part = b & (NPART - 1);
        int sub  = b >> 3;
        int lo = part * PSZ, hi = lo + PSZ;
        int stride = blocksPerPart * 256;
        for (int i = sub * 256 + threadIdx.x; i < N_EDGES; i += stride) {
            int d = __builtin_nontemporal_load(&dst[i]);
            if (d >= lo && d < hi) atomicAdd(&deg[d], 1);
        }
        return;
    }
    u16   (*As)[136] = (u16(*)[136])smem;
    float (*Ct)[132] = (float(*)[132])smem;
    __shared__ u16 alv[128], arv[128];
    const bool isf32 = (*dflag != 0);
    int tid = threadIdx.x;
    if (tid < 128) {
        alv[tid] = f2bf(ldin(alw, tid, isf32));
        arv[tid] = f2bf(ldin(arw, tid, isf32));
    }
    int rowBase = blockIdx.x * GROWS;
    for (int t = tid; t < GROWS * 32; t += 256) {
        int r = t >> 5, q = t & 31;
        int n = rowBase + r;
        if (EXT) {
            float4 v = make_float4(0.f, 0.f, 0.f, 0.f);
            if (n < N_NODES) v = ldin4(A, n * 32 + q, isf32);
            ushort4 u; u.x = f2bf(v.x); u.y = f2bf(v.y); u.z = f2bf(v.z); u.w = f2bf(v.w);
            *(ushort4*)&As[r][q * 4] = u;
        } else {
            ushort4 u = make_ushort4(0, 0, 0, 0);
            if (n < N_NODES)
                u = *(const ushort4*)((const u16*)A + (size_t)(q >> 3) * PS + (size_t)n * 32 + (q & 7) * 4);
            *(ushort4*)&As[r][q * 4] = u;
        }
    }
    int wv = tid >> 6, ln = tid & 63;
    int ln15 = ln & 15, quad = ln >> 4;
    bf16x8 bfr[2][4];
    #pragma unroll
    for (int c = 0; c < 2; c++)
        #pragma unroll
        for (int kk = 0; kk < 4; kk++)
            bfr[c][kk] = *(const bf16x8*)(Wt + (wv * 32 + c * 16 + ln15) * FDIM + kk * 32 + quad * 8);
    __syncthreads();
    f32x4 acc[4][2] = {};
    #pragma unroll
    for (int kk = 0; kk < 4; kk++) {
        #pragma unroll
        for (int rt = 0; rt < 4; rt++) {
            bf16x8 a = *(const bf16x8*)&As[rt * 16 + ln15][kk * 32 + quad * 8];
            acc[rt][0] = __builtin_amdgcn_mfma_f32_16x16x32_bf16(a, bfr[0][kk], acc[rt][0], 0, 0, 0);
            acc[rt][1] = __builtin_amdgcn_mfma_f32_16x16x32_bf16(a, bfr[1][kk], acc[rt][1], 0, 0, 0);
        }
    }
    __syncthreads();
    #pragma unroll
    for (int rt = 0; rt < 4; rt++)
        #pragma unroll
        for (int c = 0; c < 2; c++)
            #pragma unroll
            for (int p = 0; p < 4; p++)
                Ct[rt * 16 + quad * 4 + p][wv * 32 + c * 16 + ln15] = acc[rt][c][p];
    __syncthreads();
    int jc = (tid & 31) * 4, r0 = (tid >> 5) * 8;
    #pragma unroll
    for (int r = 0; r < 8; r++) {
        int n = rowBase + r0 + r;
        if (n < N_NODES)
            st4(C + (size_t)(jc >> 5) * PS + (size_t)n * 32 + (jc & 31),
                *(const float4*)&Ct[r0 + r][jc]);
    }
    int head = tid & 7;
    #pragma unroll
    for (int rr = 0; rr < 2; rr++) {
        int row = (tid >> 3) + rr * 32;
        int n2 = rowBase + row;
        if (n2 < N_NODES) {
            float sl = 0.f, sr = 0.f;
            #pragma unroll
            for (int k = 0; k < HID; k++) {
                float v = Ct[row][head * HID + k];
                sl += v * bf2f(alv[head * HID + k]);
                sr += v * bf2f(arv[head * HID + k]);
            }
            elT[(size_t)head * N_NODES + n2] = sl;
            er[n2 * HEADS + head] = sr;
        }
    }
}

// ---------------- head-sliced attention aggregation (+ELU) ----------------
// Grid = 8 XCD-slots x ceil(NTILE/2). slot = blockIdx&7 -> XCD (round-robin dispatch);
// head-group hg = slot>>1 (2 heads, 32 cols, one 3.2MB plane). Per-XCD working set =
// plane (3.2MB) + elT slice (0.4MB) -> fits the 4MB XCD L2, so gathers become L2 hits.
// Wave: 4 nodes (sub), 4 edge slots (g), 4 col-chunks of 16B (c). Summation order per
// output column identical to the fused version (same g-slot partition + xor(4,8) tree).

__global__ void __launch_bounds__(256)
agg_h(const u16* __restrict__ featP, const float* __restrict__ elT,
      const float* __restrict__ erP, const int* __restrict__ row_ptr,
      const u16* __restrict__ srcs, u16* __restrict__ outA) {
    int slot = blockIdx.x & 7;
    int hg   = slot >> 1;
    int tile = ((blockIdx.x >> 3) << 1) + (slot & 1);
    if (tile >= NTILE) return;
    int tid = threadIdx.x;
    int wv = tid >> 6, ln = tid & 63;
    int sub = ln >> 4;            // node within wave (0..3)
    int g   = (ln >> 2) & 3;      // edge slot (0..3)
    int c   = ln & 3;             // 16B col chunk (8 cols) within the 32-col slice
    int k15 = ln & 15;
    int rowBase = tile * 16;
    int rp = 0;
    if (k15 <= 4) rp = row_ptr[rowBase + wv * 4 + k15];
    int n = rowBase + wv * 4 + sub;
    int beg = __shfl(rp, sub, 64);
    int end = __shfl(rp, sub + 1, 64);
    int h = hg * 2 + (c >> 1);
    float ern = erP[n * HEADS + h];
    const float* elh = elT + (size_t)h * N_NODES;
    const u16* fpl = featP + (size_t)hg * PS;
    float ss = 0.f;
    float acc[8] = {};
    // prefetch first src + el (OOB-safe)
    int idx0 = beg + g;
    int sN = srcs[(idx0 < end) ? idx0 : ((beg < end) ? beg : 0)];
    float eN = elh[sN];
    for (int i = beg; i < end; i += 4) {
        bool v = (i + g) < end;
        int s_cur = sN;
        float elv = eN;
        int nidx = i + 4 + g;
        sN = srcs[(nidx < end) ? nidx : beg];   // prefetch next src
        eN = elh[sN];                            // prefetch next el
        float e = elv + ern;
        e = fmaxf(e, 0.2f * e);
        float x = v ? __expf(fminf(e, 80.f)) : 0.f;
        uint4 u = *(const uint4*)(fpl + (size_t)s_cur * 32 + c * 8);
        ss += x;
        acc[0] = fmaf(x, bf2f_lo(u.x), acc[0]); acc[1] = fmaf(x, bf2f_hi(u.x), acc[1]);
        acc[2] = fmaf(x, bf2f_lo(u.y), acc[2]); acc[3] = fmaf(x, bf2f_hi(u.y), acc[3]);
        acc[4] = fmaf(x, bf2f_lo(u.z), acc[4]); acc[5] = fmaf(x, bf2f_hi(u.z), acc[5]);
        acc[6] = fmaf(x, bf2f_lo(u.w), acc[6]); acc[7] = fmaf(x, bf2f_hi(u.w), acc[7]);
    }
    ss += __shfl_xor(ss, 4, 64);
    ss += __shfl_xor(ss, 8, 64);
    #pragma unroll
    for (int k = 0; k < 8; k++) {
        acc[k] += __shfl_xor(acc[k], 4, 64);
        acc[k] += __shfl_xor(acc[k], 8, 64);
    }
    if (g == 0) {
        float inv = (end > beg) ? 1.f / ss : 0.f;
        float rr[8];
        #pragma unroll
        for (int k = 0; k < 8; k++) {
            float t = acc[k] * inv;
            rr[k] = (t > 0.f) ? t : (__expf(t) - 1.f);   // ELU
        }
        uint4 o;
        o.x = pk2(rr[0], rr[1]); o.y = pk2(rr[2], rr[3]);
        o.z = pk2(rr[4], rr[5]); o.w = pk2(rr[6], rr[7]);
        *(uint4*)(outA + (size_t)hg * PS + (size_t)n * 32 + c * 8) = o;
    }
}

// ---------------- layer 4 (H=1, D=10): GEMM fused with el/er; cls padded to 16 ----------------

__global__ void __launch_bounds__(256)
gemm4(const u16* __restrict__ A, const void* __restrict__ W,
      const void* __restrict__ alw, const void* __restrict__ arw,
      float* __restrict__ out, float* __restrict__ el, float* __restrict__ er,
      const int* __restrict__ dflag) {
    __shared__ float Wl[128][16];
    const bool isf32 = (*dflag != 0);
    for (int t = threadIdx.x; t < 128 * 16; t += 256) {
        int k = t >> 4, c = t & 15;
        Wl[k][c] = (c < NCLS) ? ldin(W, k * NCLS + c, isf32) : 0.f;
    }
    __syncthreads();
    int idx = blockIdx.x * 256 + threadIdx.x;
    int n = idx >> 4, c = idx & 15;
    if (n >= N_NODES) return;
    float acc = 0.f;
    #pragma unroll
    for (int q = 0; q < 32; q++) {
        float4 v = ld4f(A + (size_t)(q >> 3) * PS + (size_t)n * 32 + (q & 7) * 4);
        acc += v.x * Wl[q * 4 + 0][c] + v.y * Wl[q * 4 + 1][c] +
               v.z * Wl[q * 4 + 2][c] + v.w * Wl[q * 4 + 3][c];
    }
    out[n * CLSP + c] = acc;    // 64B-aligned padded row
    float alc = (c < NCLS) ? ldin(alw, c, isf32) : 0.f;
    float arc = (c < NCLS) ? ldin(arw, c, isf32) : 0.f;
    float sl = acc * alc, sr = acc * arc;
    #pragma unroll
    for (int off = 8; off >= 1; off >>= 1) {
        sl += __shfl_xor(sl, off, 64);
        sr += __shfl_xor(sr, off, 64);
    }
    if (c == 0) { el[n] = sl; er[n] = sr; }
}

// ---------------- final aggregation: 4 nodes per wave (16 lanes each) ----------------

__global__ void __launch_bounds__(256)
agg4(const float* __restrict__ feat, const float* __restrict__ el,
     const float* __restrict__ er, const int* __restrict__ row_ptr,
     const u16* __restrict__ srcs, void* __restrict__ out,
     const int* __restrict__ dflag) {
    const bool isf32 = (*dflag != 0);
    int wid = (blockIdx.x * 256 + threadIdx.x) >> 6;
    int lane = threadIdx.x & 63;
    int g = lane >> 4, t = lane & 15;
    int node = wid * 4 + g;
    bool vn = node < N_NODES;
    int nn = vn ? node : 0;
    int beg = row_ptr[nn];
    int end = vn ? row_ptr[nn + 1] : beg;
    float ern = er[nn];
    int deg = end - beg;
    int mx = deg;
    mx = max(mx, __shfl_xor(mx, 16, 64));
    mx = max(mx, __shfl_xor(mx, 32, 64));
    float ssA = 0.f, ssB = 0.f, aA = 0.f, aB = 0.f;
    int k = 0;
    for (; k + 1 < mx; k += 2) {
        int i0 = beg + k, i1 = i0 + 1;
        bool v0 = i0 < end, v1 = i1 < end;
        int s0 = srcs[v0 ? i0 : beg];
        int s1 = srcs[v1 ? i1 : beg];
        float e0 = el[s0] + ern;
        float e1 = el[s1] + ern;
        float f0 = feat[s0 * CLSP + t];
        float f1 = feat[s1 * CLSP + t];
        e0 = fmaxf(e0, 0.2f * e0); e1 = fmaxf(e1, 0.2f * e1);
        float x0 = v0 ? __expf(fminf(e0, 80.f)) : 0.f;
        float x1 = v1 ? __expf(fminf(e1, 80.f)) : 0.f;
        ssA += x0; ssB += x1;
        aA = fmaf(x0, f0, aA);
        aB = fmaf(x1, f1, aB);
    }
    if (k < mx) {
        int i0 = beg + k;
        bool v0 = i0 < end;
        int s0 = srcs[v0 ? i0 : beg];
        float e0 = el[s0] + ern;
        e0 = fmaxf(e0, 0.2f * e0);
        float x0 = v0 ? __expf(fminf(e0, 80.f)) : 0.f;
        ssA += x0;
        aA = fmaf(x0, feat[s0 * CLSP + t], aA);
    }
    float ss = ssA + ssB, a = aA + aB;
    if (vn && t < NCLS) {
        float r = (deg > 0) ? a / ss : 0.f;
        if (isf32) ((float*)out)[node * NCLS + t] = r;
        else       ((u16*)out)[node * NCLS + t] = f2bf(r);
    }
}

// ---------------- launch ----------------

extern "C" void kernel_launch(void* const* d_in, const int* in_sizes, int n_in,
                              void* d_out, int out_size, void* d_ws, size_t ws_size,
                              hipStream_t stream) {
    const void* h_in = d_in[0];
    const int* src   = (const int*)d_in[1];
    const int* dst   = (const int*)d_in[2];
    const void *W[5], *al[5], *ar[5];
    for (int l = 0; l < 5; l++) {
        W[l]  = d_in[3 + 3 * l];
        al[l] = d_in[4 + 3 * l];
        ar[l] = d_in[5 + 3 * l];
    }

    char* ws = (char*)d_ws;
    size_t off = 0;
    auto alloc = [&](size_t bytes) {
        void* p = ws + off;
        off = (off + bytes + 255) & ~(size_t)255;
        return p;
    };
    int* dflag    = (int*)alloc(4);
    u16* feat0    = (u16*)alloc((size_t)N_NODES * FDIM * sizeof(u16)); // plane layout, ping
    u16* feat1    = (u16*)alloc((size_t)N_NODES * FDIM * sizeof(u16)); // plane layout, pong
    u16* aggA     = (u16*)alloc((size_t)N_NODES * FDIM * sizeof(u16)); // plane layout, agg out
    u16* Wt       = (u16*)alloc(4ull * FDIM * FDIM * sizeof(u16));     // transposed bf16 weights
    float* elT0   = (float*)alloc((size_t)N_NODES * HEADS * 4);        // [head][node]
    float* er0    = (float*)alloc((size_t)N_NODES * HEADS * 4);        // [node][head]
    float* elT1   = (float*)alloc((size_t)N_NODES * HEADS * 4);
    float* er1    = (float*)alloc((size_t)N_NODES * HEADS * 4);
    float* el4    = (float*)alloc((size_t)N_NODES * 4);
    float* er4    = (float*)alloc((size_t)N_NODES * 4);
    float* cls    = (float*)alloc((size_t)N_NODES * CLSP * 4);
    int* deg      = (int*)alloc((size_t)N_NODES * 4);
    int* row_ptr  = (int*)alloc((size_t)(N_NODES + 1) * 4);
    int* cursor   = (int*)alloc((size_t)N_NODES * 4);
    u16* srcs     = (u16*)alloc((size_t)N_EDGES * 2);
    int* bsum     = (int*)alloc(256 * 4);

    const int NB  = (N_NODES + SCB - 1) / SCB;         // 98 scan blocks
    const int GB  = (N_NODES + GROWS - 1) / GROWS;     // 782 gemm blocks
    const int CPP = 128;                               // count blocks per partition
    const int BPP = 256;                               // fill blocks per partition
    const int AB  = 8 * ((NTILE + 1) / 2);             // 12504 agg blocks (8 XCD slots)

    detect_and_zero<<<1 + (N_NODES + 255) / 256, 256, 0, stream>>>(
        (const u16*)W[0], FDIM * FDIM, dflag, deg);
    prep_wt<<<dim3((FDIM * FDIM + 255) / 256, 4), 256, 0, stream>>>(
        W[0], W[1], W[2], W[3], Wt, dflag);

    // layer-0 GEMM overlapped with CSR degree count (independent)
    gemm_mfma<true><<<GB + NPART * CPP, 256, 0, stream>>>(
        h_in, Wt, al[0], ar[0], feat0, elT0, er0, dflag, dst, deg, GB, CPP);

    deg_bsum<<<NB, SCB, 0, stream>>>(deg, bsum);
    deg_scan2<<<NB, SCB, 0, stream>>>(deg, bsum, row_ptr, cursor);
    fill_csr_x<<<NPART * BPP, 256, 0, stream>>>(src, dst, cursor, srcs, BPP);

    // layer 0 agg -> layer 1 gemm
    agg_h<<<AB, 256, 0, stream>>>(feat0, elT0, er0, row_ptr, srcs, aggA);
    gemm_mfma<false><<<GB, 256, 0, stream>>>(
        aggA, Wt + 1 * FDIM * FDIM, al[1], ar[1], feat1, elT1, er1, dflag,
        nullptr, nullptr, GB, 0);
    // layer 1 agg -> layer 2 gemm
    agg_h<<<AB, 256, 0, stream>>>(feat1, elT1, er1, row_ptr, srcs, aggA);
    gemm_mfma<false><<<GB, 256, 0, stream>>>(
        aggA, Wt + 2 * FDIM * FDIM, al[2], ar[2], feat0, elT0, er0, dflag,
        nullptr, nullptr, GB, 0);
    // layer 2 agg -> layer 3 gemm
    agg_h<<<AB, 256, 0, stream>>>(feat0, elT0, er0, row_ptr, srcs, aggA);
    gemm_mfma<false><<<GB, 256, 0, stream>>>(
        aggA, Wt + 3 * FDIM * FDIM, al[3], ar[3], feat1, elT1, er1, dflag,
        nullptr, nullptr, GB, 0);
    // layer 3 agg -> classifier gemm -> final agg
    agg_h<<<AB, 256, 0, stream>>>(feat1, elT1, er1, row_ptr, srcs, aggA);
    gemm4<<<(N_NODES * 16 + 255) / 256, 256, 0, stream>>>(
        aggA, W[4], al[4], ar[4], cls, el4, er4, dflag);
    agg4<<<(N_NODES / 16 + 1), 256, 0, stream>>>(cls, el4, er4, row_ptr, srcs, d_out, dflag);
}

// Round 6
// 408.635 us; speedup vs baseline: 1.3395x; 1.1594x over previous
//
#include <hip/hip_runtime.h>
#include <hip/hip_bf16.h>

#define N_NODES 50000
#define N_EDGES 800000
#define FDIM    128
#define HEADS   8
#define HID     16
#define NCLS    10
#define CLSP    16    // padded cls row (64B aligned)
#define SCB     512   // scan block size
#define NPART   8     // XCD partitions for CSR scatter/count
#define PSZ     6250  // N_NODES / NPART
#define GROWS   64    // gemm rows per block (layer 0)
#define GR      16    // fused agg+gemm rows per block (layers 1-4); 50000/16=3125 exact

typedef unsigned short u16;
typedef __attribute__((ext_vector_type(8))) short bf16x8;
typedef __attribute__((ext_vector_type(4))) float f32x4;

__device__ __forceinline__ float bf2f(u16 u) {
    union { unsigned int i; float f; } c; c.i = ((unsigned int)u) << 16; return c.f;
}
__device__ __forceinline__ float bf2f_hi(unsigned int u) {
    union { unsigned int i; float f; } c; c.i = u & 0xffff0000u; return c.f;
}
__device__ __forceinline__ float bf2f_lo(unsigned int u) {
    union { unsigned int i; float f; } c; c.i = u << 16; return c.f;
}
__device__ __forceinline__ u16 f2bf(float f) {
    union { float f; unsigned int i; } c; c.f = f;
    unsigned int r = c.i + 0x7FFFu + ((c.i >> 16) & 1u);
    return (u16)(r >> 16);
}
__device__ __forceinline__ unsigned int pk2(float a, float b) {
    return (unsigned int)f2bf(a) | ((unsigned int)f2bf(b) << 16);
}
__device__ __forceinline__ float4 bf2f4(ushort4 u) {
    return make_float4(bf2f(u.x), bf2f(u.y), bf2f(u.z), bf2f(u.w));
}
__device__ __forceinline__ float4 ld4f(const u16* p)  { return bf2f4(*(const ushort4*)p); }
__device__ __forceinline__ void   st4(u16* p, float4 v) {
    ushort4 u; u.x = f2bf(v.x); u.y = f2bf(v.y); u.z = f2bf(v.z); u.w = f2bf(v.w);
    *(ushort4*)p = u;
}

// external-input decode (dtype resolved at runtime via flag)
__device__ __forceinline__ float ldin(const void* p, int i, bool isf32) {
    return isf32 ? ((const float*)p)[i] : bf2f(((const u16*)p)[i]);
}
__device__ __forceinline__ float4 ldin4(const void* p, int i4, bool isf32) {
    if (isf32) return ((const float4*)p)[i4];
    return bf2f4(((const ushort4*)p)[i4]);
}

// ---------------- dtype detection (W0 scan) + deg zeroing (merged grid) ----------------
__global__ void detect_and_zero(const u16* __restrict__ w, int n, int* __restrict__ flag,
                                int* __restrict__ deg) {
    if (blockIdx.x != 0) {
        int i = (blockIdx.x - 1) * 256 + threadIdx.x;
        if (i < N_NODES) deg[i] = 0;
        return;
    }
    __shared__ int s_huge, s_zero;
    if (threadIdx.x == 0) { s_huge = 0; s_zero = 0; }
    __syncthreads();
    int huge = 0, zero = 0;
    for (int i = threadIdx.x * 8; i < n; i += 256 * 8) {
        ushort4 a = *(const ushort4*)(w + i);
        ushort4 b = *(const ushort4*)(w + i + 4);
        u16 vals[8] = { a.x, a.y, a.z, a.w, b.x, b.y, b.z, b.w };
        #pragma unroll
        for (int k = 0; k < 8; k++) {
            float v = bf2f(vals[k]);
            if (fabsf(v) > 1e9f || v != v) huge++;
            if (vals[k] == 0) zero++;
        }
    }
    atomicAdd(&s_huge, huge);
    atomicAdd(&s_zero, zero);
    __syncthreads();
    if (threadIdx.x == 0)
        *flag = (s_huge > 0 || s_zero > n / 4) ? 1 : 0;
}

// ---------------- W transpose to bf16 (Wt[n][k]) for MFMA B-frags ----------------
__global__ void prep_wt(const void* __restrict__ W0, const void* __restrict__ W1,
                        const void* __restrict__ W2, const void* __restrict__ W3,
                        u16* __restrict__ Wt, const int* __restrict__ dflag) {
    const bool isf32 = (*dflag != 0);
    int l = blockIdx.y;
    const void* W = (l == 0) ? W0 : (l == 1) ? W1 : (l == 2) ? W2 : W3;
    int i = blockIdx.x * 256 + threadIdx.x;
    if (i >= FDIM * FDIM) return;
    int n = i >> 7, k = i & 127;
    Wt[l * FDIM * FDIM + n * FDIM + k] = f2bf(ldin(W, k * FDIM + n, isf32));
}

// ---------------- CSR build ----------------

__global__ void __launch_bounds__(SCB)
deg_bsum(const int* __restrict__ deg, int* __restrict__ bsum) {
    int i = blockIdx.x * SCB + threadIdx.x;
    int v = (i < N_NODES) ? deg[i] : 0;
    for (int off = 32; off; off >>= 1) v += __shfl_down(v, off, 64);
    __shared__ int wsum[SCB / 64];
    int wv = threadIdx.x >> 6, ln = threadIdx.x & 63;
    if (ln == 0) wsum[wv] = v;
    __syncthreads();
    if (threadIdx.x == 0) {
        int s = 0;
        #pragma unroll
        for (int k = 0; k < SCB / 64; k++) s += wsum[k];
        bsum[blockIdx.x] = s;
    }
}

// block scan of deg; each block sums bsum[0..blockIdx.x-1] itself (one wave)
__global__ void __launch_bounds__(SCB)
deg_scan2(const int* __restrict__ deg, const int* __restrict__ bsum,
          int* __restrict__ row_ptr, int* __restrict__ cursor) {
    __shared__ int sd[SCB];
    __shared__ int spfx;
    int tid = threadIdx.x;
    int i = blockIdx.x * SCB + tid;
    int v = (i < N_NODES) ? deg[i] : 0;
    sd[tid] = v;
    if (tid < 64) {
        int p = 0;
        if (tid < (int)blockIdx.x) p = bsum[tid];
        if (64 + tid < (int)blockIdx.x) p += bsum[64 + tid];
        for (int off = 32; off; off >>= 1) p += __shfl_down(p, off, 64);
        if (tid == 0) spfx = p;
    }
    __syncthreads();
    for (int off = 1; off < SCB; off <<= 1) {
        int t = (tid >= off) ? sd[tid - off] : 0;
        __syncthreads();
        sd[tid] += t;
        __syncthreads();
    }
    if (i < N_NODES) {
        int ex = sd[tid] - v + spfx;
        row_ptr[i] = ex;
        cursor[i] = ex;
    }
    if (blockIdx.x == 0 && tid == 0) row_ptr[N_NODES] = N_EDGES;
}

// XCD-partitioned scatter into u16 srcs (node ids < 65536).
__global__ void __launch_bounds__(256)
fill_csr_x(const int* __restrict__ src, const int* __restrict__ dst,
           int* __restrict__ cursor, u16* __restrict__ srcs, int blocksPerPart) {
    int part = blockIdx.x & (NPART - 1);
    int sub  = blockIdx.x >> 3;
    int lo = part * PSZ, hi = lo + PSZ;
    int stride = blocksPerPart * 256;
    for (int i = sub * 256 + threadIdx.x; i < N_EDGES; i += stride) {
        int d = __builtin_nontemporal_load(&dst[i]);
        if (d >= lo && d < hi) {
            int pos = atomicAdd(&cursor[d], 1);
            srcs[pos] = (u16)__builtin_nontemporal_load(&src[i]);
        }
    }
}

// ---------------- merged: layer-0 MFMA GEMM (+el/er)  ||  CSR degree count ----------------

__global__ void __launch_bounds__(256)
gemm0_count(const void* __restrict__ A, const u16* __restrict__ Wt,
            const void* __restrict__ alw, const void* __restrict__ arw,
            u16* __restrict__ C, float* __restrict__ el, float* __restrict__ er,
            const int* __restrict__ dflag,
            const int* __restrict__ dst, int* __restrict__ deg,
            int gemmBlocks, int blocksPerPart) {
    __shared__ __align__(16) char smem[GROWS * 132 * 4];  // Ct fp32 aliases As bf16
    if ((int)blockIdx.x >= gemmBlocks) {
        int b = blockIdx.x - gemmBlocks;
        int part = b & (NPART - 1);
        int sub  = b >> 3;
        int lo = part * PSZ, hi = lo + PSZ;
        int stride = blocksPerPart * 256;
        for (int i = sub * 256 + threadIdx.x; i < N_EDGES; i += stride) {
            int d = __builtin_nontemporal_load(&dst[i]);
            if (d >= lo && d < hi) atomicAdd(&deg[d], 1);
        }
        return;
    }
    u16   (*As)[136] = (u16(*)[136])smem;
    float (*Ct)[132] = (float(*)[132])smem;
    __shared__ u16 alv[128], arv[128];
    const bool isf32 = (*dflag != 0);
    int tid = threadIdx.x;
    if (tid < 128) {
        alv[tid] = f2bf(ldin(alw, tid, isf32));
        arv[tid] = f2bf(ldin(arw, tid, isf32));
    }
    int rowBase = blockIdx.x * GROWS;
    for (int t = tid; t < GROWS * 32; t += 256) {
        int r = t >> 5, q = t & 31;
        int n = rowBase + r;
        float4 v = make_float4(0.f, 0.f, 0.f, 0.f);
        if (n < N_NODES) v = ldin4(A, n * 32 + q, isf32);
        ushort4 u; u.x = f2bf(v.x); u.y = f2bf(v.y); u.z = f2bf(v.z); u.w = f2bf(v.w);
        *(ushort4*)&As[r][q * 4] = u;
    }
    int wv = tid >> 6, ln = tid & 63;
    int ln15 = ln & 15, quad = ln >> 4;
    bf16x8 bfr[2][4];
    #pragma unroll
    for (int c = 0; c < 2; c++)
        #pragma unroll
        for (int kk = 0; kk < 4; kk++)
            bfr[c][kk] = *(const bf16x8*)(Wt + (wv * 32 + c * 16 + ln15) * FDIM + kk * 32 + quad * 8);
    __syncthreads();
    f32x4 acc[4][2] = {};
    #pragma unroll
    for (int kk = 0; kk < 4; kk++) {
        #pragma unroll
        for (int rt = 0; rt < 4; rt++) {
            bf16x8 a = *(const bf16x8*)&As[rt * 16 + ln15][kk * 32 + quad * 8];
            acc[rt][0] = __builtin_amdgcn_mfma_f32_16x16x32_bf16(a, bfr[0][kk], acc[rt][0], 0, 0, 0);
            acc[rt][1] = __builtin_amdgcn_mfma_f32_16x16x32_bf16(a, bfr[1][kk], acc[rt][1], 0, 0, 0);
        }
    }
    __syncthreads();
    #pragma unroll
    for (int rt = 0; rt < 4; rt++)
        #pragma unroll
        for (int c = 0; c < 2; c++)
            #pragma unroll
            for (int p = 0; p < 4; p++)
                Ct[rt * 16 + quad * 4 + p][wv * 32 + c * 16 + ln15] = acc[rt][c][p];
    __syncthreads();
    int jc = (tid & 31) * 4, r0 = (tid >> 5) * 8;
    #pragma unroll
    for (int r = 0; r < 8; r++) {
        int n = rowBase + r0 + r;
        if (n < N_NODES)
            st4(C + (size_t)n * FDIM + jc, *(const float4*)&Ct[r0 + r][jc]);
    }
    int head = tid & 7;
    #pragma unroll
    for (int rr = 0; rr < 2; rr++) {
        int row = (tid >> 3) + rr * 32;
        int n2 = rowBase + row;
        if (n2 < N_NODES) {
            float sl = 0.f, sr = 0.f;
            #pragma unroll
            for (int k = 0; k < HID; k++) {
                float v = Ct[row][head * HID + k];
                sl += v * bf2f(alv[head * HID + k]);
                sr += v * bf2f(arv[head * HID + k]);
            }
            el[n2 * HEADS + head] = sl;
            er[n2 * HEADS + head] = sr;
        }
    }
}

// ---------------- shared agg phase: 16 nodes/block -> ELU'd bf16 rows in LDS ----------------
// Wave layout: 4 nodes (sub=ln>>4), 4 edge slots (g=(ln>>2)&3), 2 heads/lane (q2=ln&3).
// 16 edges in flight/wave; srcs, el AND feat row all prefetched one step ahead
// (no exposed dependent hop in steady state). 32-bit feat addressing.

__device__ __forceinline__ void agg_rows(
    const u16* __restrict__ featP, const float* __restrict__ elP,
    const float* __restrict__ erP, const int* __restrict__ row_ptr,
    const u16* __restrict__ srcs, int rowBase, int tid, u16 (*As)[136]) {
    int wv = tid >> 6, ln = tid & 63;
    int sub = ln >> 4;            // node within wave (0..3)
    int g   = (ln >> 2) & 3;      // edge slot (0..3)
    int q2  = ln & 3;             // head pair
    int rp = 0;
    int k15 = ln & 15;
    {
        int ridx = rowBase + wv * 4 + k15;
        if (k15 <= 4) rp = row_ptr[ridx > N_NODES ? N_NODES : ridx];
    }
    int r = wv * 4 + sub;
    int n = rowBase + r;
    int beg = __shfl(rp, sub, 64);
    int end = __shfl(rp, sub + 1, 64);
    int nc = (n < N_NODES) ? n : 0;
    float2 erv = *(const float2*)&erP[nc * HEADS + q2 * 2];
    float ss0 = 0.f, ss1 = 0.f;
    float acc[32] = {};
    // prefetch first src + el + feat row (OOB-safe)
    int idx0 = beg + g;
    int sN = srcs[(idx0 < end) ? idx0 : ((beg < end) ? beg : 0)];
    float2 elN_ = *(const float2*)&elP[sN * HEADS + q2 * 2];
    const u16* frN = featP + (unsigned)(sN * FDIM) + q2 * 32;
    uint4 p0 = *(const uint4*)frN;
    uint4 p1 = *(const uint4*)(frN + 8);
    uint4 p2 = *(const uint4*)(frN + 16);
    uint4 p3 = *(const uint4*)(frN + 24);
    for (int i = beg; i < end; i += 4) {
        bool v = (i + g) < end;
        float2 elv = elN_;
        uint4 u0 = p0, u1 = p1, u2 = p2, u3 = p3;
        int nidx = i + 4 + g;
        sN = srcs[(nidx < end) ? nidx : beg];              // prefetch next src
        elN_ = *(const float2*)&elP[sN * HEADS + q2 * 2];  // prefetch next el
        const u16* fr2 = featP + (unsigned)(sN * FDIM) + q2 * 32;
        p0 = *(const uint4*)fr2;                           // prefetch next feat row
        p1 = *(const uint4*)(fr2 + 8);
        p2 = *(const uint4*)(fr2 + 16);
        p3 = *(const uint4*)(fr2 + 24);
        float e0 = elv.x + erv.x;
        float e1 = elv.y + erv.y;
        e0 = fmaxf(e0, 0.2f * e0);
        e1 = fmaxf(e1, 0.2f * e1);
        float x0 = v ? __expf(fminf(e0, 80.f)) : 0.f;
        float x1 = v ? __expf(fminf(e1, 80.f)) : 0.f;
        ss0 += x0; ss1 += x1;
        acc[0]  = fmaf(x0, bf2f_lo(u0.x), acc[0]);  acc[1]  = fmaf(x0, bf2f_hi(u0.x), acc[1]);
        acc[2]  = fmaf(x0, bf2f_lo(u0.y), acc[2]);  acc[3]  = fmaf(x0, bf2f_hi(u0.y), acc[3]);
        acc[4]  = fmaf(x0, bf2f_lo(u0.z), acc[4]);  acc[5]  = fmaf(x0, bf2f_hi(u0.z), acc[5]);
        acc[6]  = fmaf(x0, bf2f_lo(u0.w), acc[6]);  acc[7]  = fmaf(x0, bf2f_hi(u0.w), acc[7]);
        acc[8]  = fmaf(x0, bf2f_lo(u1.x), acc[8]);  acc[9]  = fmaf(x0, bf2f_hi(u1.x), acc[9]);
        acc[10] = fmaf(x0, bf2f_lo(u1.y), acc[10]); acc[11] = fmaf(x0, bf2f_hi(u1.y), acc[11]);
        acc[12] = fmaf(x0, bf2f_lo(u1.z), acc[12]); acc[13] = fmaf(x0, bf2f_hi(u1.z), acc[13]);
        acc[14] = fmaf(x0, bf2f_lo(u1.w), acc[14]); acc[15] = fmaf(x0, bf2f_hi(u1.w), acc[15]);
        acc[16] = fmaf(x1, bf2f_lo(u2.x), acc[16]); acc[17] = fmaf(x1, bf2f_hi(u2.x), acc[17]);
        acc[18] = fmaf(x1, bf2f_lo(u2.y), acc[18]); acc[19] = fmaf(x1, bf2f_hi(u2.y), acc[19]);
        acc[20] = fmaf(x1, bf2f_lo(u2.z), acc[20]); acc[21] = fmaf(x1, bf2f_hi(u2.z), acc[21]);
        acc[22] = fmaf(x1, bf2f_lo(u2.w), acc[22]); acc[23] = fmaf(x1, bf2f_hi(u2.w), acc[23]);
        acc[24] = fmaf(x1, bf2f_lo(u3.x), acc[24]); acc[25] = fmaf(x1, bf2f_hi(u3.x), acc[25]);
        acc[26] = fmaf(x1, bf2f_lo(u3.y), acc[26]); acc[27] = fmaf(x1, bf2f_hi(u3.y), acc[27]);
        acc[28] = fmaf(x1, bf2f_lo(u3.z), acc[28]); acc[29] = fmaf(x1, bf2f_hi(u3.z), acc[29]);
        acc[30] = fmaf(x1, bf2f_lo(u3.w), acc[30]); acc[31] = fmaf(x1, bf2f_hi(u3.w), acc[31]);
    }
    ss0 += __shfl_xor(ss0, 4, 64);
    ss0 += __shfl_xor(ss0, 8, 64);
    ss1 += __shfl_xor(ss1, 4, 64);
    ss1 += __shfl_xor(ss1, 8, 64);
    #pragma unroll
    for (int k = 0; k < 32; k++) {
        acc[k] += __shfl_xor(acc[k], 4, 64);
        acc[k] += __shfl_xor(acc[k], 8, 64);
    }
    if (g == 0) {
        float inv0 = (end > beg) ? 1.f / ss0 : 0.f;
        float inv1 = (end > beg) ? 1.f / ss1 : 0.f;
        float rr[32];
        #pragma unroll
        for (int k = 0; k < 32; k++) {
            float t = acc[k] * ((k < 16) ? inv0 : inv1);
            rr[k] = (t > 0.f) ? t : (__expf(t) - 1.f);   // ELU
        }
        uint4 o0, o1, o2, o3;
        o0.x = pk2(rr[0],  rr[1]);  o0.y = pk2(rr[2],  rr[3]);
        o0.z = pk2(rr[4],  rr[5]);  o0.w = pk2(rr[6],  rr[7]);
        o1.x = pk2(rr[8],  rr[9]);  o1.y = pk2(rr[10], rr[11]);
        o1.z = pk2(rr[12], rr[13]); o1.w = pk2(rr[14], rr[15]);
        o2.x = pk2(rr[16], rr[17]); o2.y = pk2(rr[18], rr[19]);
        o2.z = pk2(rr[20], rr[21]); o2.w = pk2(rr[22], rr[23]);
        o3.x = pk2(rr[24], rr[25]); o3.y = pk2(rr[26], rr[27]);
        o3.z = pk2(rr[28], rr[29]); o3.w = pk2(rr[30], rr[31]);
        u16* dp = &As[r][q2 * 32];
        *(uint4*)dp        = o0;
        *(uint4*)(dp + 8)  = o1;
        *(uint4*)(dp + 16) = o2;
        *(uint4*)(dp + 24) = o3;
    }
}

// ---------------- fused agg (layer l-1, ELU) + MFMA GEMM (layer l) ----------------

__global__ void __launch_bounds__(256)
fused_agg_gemm(const u16* __restrict__ featP, const float* __restrict__ elP,
               const float* __restrict__ erP, const int* __restrict__ row_ptr,
               const u16* __restrict__ srcs, const u16* __restrict__ Wt,
               const void* __restrict__ alw, const void* __restrict__ arw,
               u16* __restrict__ featN, float* __restrict__ elN, float* __restrict__ erN,
               const int* __restrict__ dflag) {
    __shared__ __align__(16) char smem[GR * 132 * 4];   // Ct f32 (8448B) aliases As bf16 (4352B)
    u16   (*As)[136] = (u16(*)[136])smem;
    float (*Ct)[132] = (float(*)[132])smem;
    __shared__ u16 alv[128], arv[128];
    const bool isf32 = (*dflag != 0);
    int tid = threadIdx.x;
    if (tid < 128) {
        alv[tid] = f2bf(ldin(alw, tid, isf32));
        arv[tid] = f2bf(ldin(arw, tid, isf32));
    }
    int rowBase = blockIdx.x * GR;
    agg_rows(featP, elP, erP, row_ptr, srcs, rowBase, tid, As);
    int wv = tid >> 6, ln = tid & 63;
    int ln15 = ln & 15, quad = ln >> 4;
    bf16x8 bfr[2][4];
    #pragma unroll
    for (int c = 0; c < 2; c++)
        #pragma unroll
        for (int kk = 0; kk < 4; kk++)
            bfr[c][kk] = *(const bf16x8*)(Wt + (wv * 32 + c * 16 + ln15) * FDIM + kk * 32 + quad * 8);
    __syncthreads();
    // ---- GEMM phase (16 rows; wave wv -> cols wv*32..+31) ----
    f32x4 acc2[2] = {};
    #pragma unroll
    for (int kk = 0; kk < 4; kk++) {
        bf16x8 a = *(const bf16x8*)&As[ln15][kk * 32 + quad * 8];
        acc2[0] = __builtin_amdgcn_mfma_f32_16x16x32_bf16(a, bfr[0][kk], acc2[0], 0, 0, 0);
        acc2[1] = __builtin_amdgcn_mfma_f32_16x16x32_bf16(a, bfr[1][kk], acc2[1], 0, 0, 0);
    }
    __syncthreads();   // As reads done; smem becomes Ct
    #pragma unroll
    for (int c = 0; c < 2; c++)
        #pragma unroll
        for (int p = 0; p < 4; p++)
            Ct[quad * 4 + p][wv * 32 + c * 16 + ln15] = acc2[c][p];
    __syncthreads();
    // coalesced bf16 feat store: thread stores 2 rows x 4 cols
    int jc = (tid & 31) * 4, r0s = (tid >> 5) * 2;
    #pragma unroll
    for (int r2 = 0; r2 < 2; r2++) {
        int n = rowBase + r0s + r2;
        if (n < N_NODES)
            st4(featN + (size_t)n * FDIM + jc, *(const float4*)&Ct[r0s + r2][jc]);
    }
    // fused el/er: 16 rows x 8 heads = 128 items
    if (tid < 128) {
        int head = tid & 7, row2 = tid >> 3;
        int n2 = rowBase + row2;
        if (n2 < N_NODES) {
            float sl = 0.f, sr = 0.f;
            #pragma unroll
            for (int k = 0; k < HID; k++) {
                float v = Ct[row2][head * HID + k];
                sl += v * bf2f(alv[head * HID + k]);
                sr += v * bf2f(arv[head * HID + k]);
            }
            elN[n2 * HEADS + head] = sl;
            erN[n2 * HEADS + head] = sr;
        }
    }
}

// ---------------- fused agg (layer 3, ELU) + classifier GEMM (layer 4) + el/er ----------------

__global__ void __launch_bounds__(256)
fused_agg_cls(const u16* __restrict__ featP, const float* __restrict__ elP,
              const float* __restrict__ erP, const int* __restrict__ row_ptr,
              const u16* __restrict__ srcs, const void* __restrict__ W4,
              const void* __restrict__ alw, const void* __restrict__ arw,
              float* __restrict__ cls, float* __restrict__ elN, float* __restrict__ erN,
              const int* __restrict__ dflag) {
    __shared__ __align__(16) u16 As[GR][136];
    __shared__ float Wl[128][16];
    const bool isf32 = (*dflag != 0);
    int tid = threadIdx.x;
    for (int t = tid; t < 128 * 16; t += 256) {
        int k = t >> 4, c = t & 15;
        Wl[k][c] = (c < NCLS) ? ldin(W4, k * NCLS + c, isf32) : 0.f;
    }
    int rowBase = blockIdx.x * GR;
    agg_rows(featP, elP, erP, row_ptr, srcs, rowBase, tid, As);
    __syncthreads();
    // classifier: 16 rows x 16 cols, 1 output/thread
    int c = tid & 15;
    int row = tid >> 4;
    int n = rowBase + row;
    float alc = (c < NCLS) ? ldin(alw, c, isf32) : 0.f;
    float arc = (c < NCLS) ? ldin(arw, c, isf32) : 0.f;
    float acc = 0.f;
    #pragma unroll
    for (int qq = 0; qq < 32; qq++) {
        float4 v = ld4f(&As[row][qq * 4]);
        acc += v.x * Wl[qq * 4 + 0][c] + v.y * Wl[qq * 4 + 1][c] +
               v.z * Wl[qq * 4 + 2][c] + v.w * Wl[qq * 4 + 3][c];
    }
    if (n < N_NODES) cls[n * CLSP + c] = acc;
    float sl = acc * alc, sr = acc * arc;
    #pragma unroll
    for (int off = 8; off >= 1; off >>= 1) {
        sl += __shfl_xor(sl, off, 64);
        sr += __shfl_xor(sr, off, 64);
    }
    if (c == 0 && n < N_NODES) { elN[n] = sl; erN[n] = sr; }
}

// ---------------- final aggregation: 4 nodes per wave (16 lanes each) ----------------

__global__ void __launch_bounds__(256)
agg4(const float* __restrict__ feat, const float* __restrict__ el,
     const float* __restrict__ er, const int* __restrict__ row_ptr,
     const u16* __restrict__ srcs, void* __restrict__ out,
     const int* __restrict__ dflag) {
    const bool isf32 = (*dflag != 0);
    int wid = (blockIdx.x * 256 + threadIdx.x) >> 6;
    int lane = threadIdx.x & 63;
    int g = lane >> 4, t = lane & 15;
    int node = wid * 4 + g;
    bool vn = node < N_NODES;
    int nn = vn ? node : 0;
    int beg = row_ptr[nn];
    int end = vn ? row_ptr[nn + 1] : beg;
    float ern = er[nn];
    int deg = end - beg;
    int mx = deg;
    mx = max(mx, __shfl_xor(mx, 16, 64));
    mx = max(mx, __shfl_xor(mx, 32, 64));
    float ssA = 0.f, ssB = 0.f, aA = 0.f, aB = 0.f;
    int k = 0;
    for (; k + 1 < mx; k += 2) {
        int i0 = beg + k, i1 = i0 + 1;
        bool v0 = i0 < end, v1 = i1 < end;
        int s0 = srcs[v0 ? i0 : beg];
        int s1 = srcs[v1 ? i1 : beg];
        float e0 = el[s0] + ern;
        float e1 = el[s1] + ern;
        float f0 = feat[s0 * CLSP + t];
        float f1 = feat[s1 * CLSP + t];
        e0 = fmaxf(e0, 0.2f * e0); e1 = fmaxf(e1, 0.2f * e1);
        float x0 = v0 ? __expf(fminf(e0, 80.f)) : 0.f;
        float x1 = v1 ? __expf(fminf(e1, 80.f)) : 0.f;
        ssA += x0; ssB += x1;
        aA = fmaf(x0, f0, aA);
        aB = fmaf(x1, f1, aB);
    }
    if (k < mx) {
        int i0 = beg + k;
        bool v0 = i0 < end;
        int s0 = srcs[v0 ? i0 : beg];
        float e0 = el[s0] + ern;
        e0 = fmaxf(e0, 0.2f * e0);
        float x0 = v0 ? __expf(fminf(e0, 80.f)) : 0.f;
        ssA += x0;
        aA = fmaf(x0, feat[s0 * CLSP + t], aA);
    }
    float ss = ssA + ssB, a = aA + aB;
    if (vn && t < NCLS) {
        float r = (deg > 0) ? a / ss : 0.f;
        if (isf32) ((float*)out)[node * NCLS + t] = r;
        else       ((u16*)out)[node * NCLS + t] = f2bf(r);
    }
}

// ---------------- launch ----------------

extern "C" void kernel_launch(void* const* d_in, const int* in_sizes, int n_in,
                              void* d_out, int out_size, void* d_ws, size_t ws_size,
                              hipStream_t stream) {
    const void* h_in = d_in[0];
    const int* src   = (const int*)d_in[1];
    const int* dst   = (const int*)d_in[2];
    const void *W[5], *al[5], *ar[5];
    for (int l = 0; l < 5; l++) {
        W[l]  = d_in[3 + 3 * l];
        al[l] = d_in[4 + 3 * l];
        ar[l] = d_in[5 + 3 * l];
    }

    char* ws = (char*)d_ws;
    size_t off = 0;
    auto alloc = [&](size_t bytes) {
        void* p = ws + off;
        off = (off + bytes + 255) & ~(size_t)255;
        return p;
    };
    int* dflag   = (int*)alloc(4);
    u16* feat0   = (u16*)alloc((size_t)N_NODES * FDIM * sizeof(u16)); // ping
    u16* feat1   = (u16*)alloc((size_t)N_NODES * FDIM * sizeof(u16)); // pong
    u16* Wt      = (u16*)alloc(4ull * FDIM * FDIM * sizeof(u16));     // transposed bf16 weights
    float* el0   = (float*)alloc((size_t)N_NODES * HEADS * 4);
    float* er0   = (float*)alloc((size_t)N_NODES * HEADS * 4);
    float* el1   = (float*)alloc((size_t)N_NODES * HEADS * 4);
    float* er1   = (float*)alloc((size_t)N_NODES * HEADS * 4);
    float* cls   = (float*)alloc((size_t)N_NODES * CLSP * 4);
    int* deg     = (int*)alloc((size_t)N_NODES * 4);
    int* row_ptr = (int*)alloc((size_t)(N_NODES + 1) * 4);
    int* cursor  = (int*)alloc((size_t)N_NODES * 4);
    u16* srcs    = (u16*)alloc((size_t)N_EDGES * 2);
    int* bsum    = (int*)alloc(256 * 4);

    const int NB = (N_NODES + SCB - 1) / SCB;          // 98 scan blocks
    const int GB = (N_NODES + GROWS - 1) / GROWS;      // 782 gemm0 blocks
    const int CPP = 128;                               // count blocks per partition
    const int BPP = 256;                               // fill blocks per partition
    const int FB = N_NODES / GR;                       // 3125 fused blocks (exact)

    detect_and_zero<<<1 + (N_NODES + 255) / 256, 256, 0, stream>>>(
        (const u16*)W[0], FDIM * FDIM, dflag, deg);
    prep_wt<<<dim3((FDIM * FDIM + 255) / 256, 4), 256, 0, stream>>>(
        W[0], W[1], W[2], W[3], Wt, dflag);

    // layer-0 GEMM overlapped with CSR degree count (independent)
    gemm0_count<<<GB + NPART * CPP, 256, 0, stream>>>(
        h_in, Wt, al[0], ar[0], feat0, el0, er0, dflag, dst, deg, GB, CPP);

    deg_bsum<<<NB, SCB, 0, stream>>>(deg, bsum);
    deg_scan2<<<NB, SCB, 0, stream>>>(deg, bsum, row_ptr, cursor);
    fill_csr_x<<<NPART * BPP, 256, 0, stream>>>(src, dst, cursor, srcs, BPP);

    // layers 1-3: fused agg(l-1)+gemm(l), ping-pong buffers
    fused_agg_gemm<<<FB, 256, 0, stream>>>(
        feat0, el0, er0, row_ptr, srcs, Wt + 1 * FDIM * FDIM, al[1], ar[1],
        feat1, el1, er1, dflag);
    fused_agg_gemm<<<FB, 256, 0, stream>>>(
        feat1, el1, er1, row_ptr, srcs, Wt + 2 * FDIM * FDIM, al[2], ar[2],
        feat0, el0, er0, dflag);
    fused_agg_gemm<<<FB, 256, 0, stream>>>(
        feat0, el0, er0, row_ptr, srcs, Wt + 3 * FDIM * FDIM, al[3], ar[3],
        feat1, el1, er1, dflag);
    // layer-3 aggregation fused with classifier GEMM + layer-4 el/er
    fused_agg_cls<<<FB, 256, 0, stream>>>(
        feat1, el1, er1, row_ptr, srcs, W[4], al[4], ar[4], cls, el0, er0, dflag);
    agg4<<<(N_NODES / 16 + 1), 256, 0, stream>>>(cls, el0, er0, row_ptr, srcs, d_out, dflag);
}

// Round 7
// 400.488 us; speedup vs baseline: 1.3668x; 1.0203x over previous
//
#include <hip/hip_runtime.h>
#include <hip/hip_bf16.h>

#define N_NODES 50000
#define N_EDGES 800000
#define FDIM    128
#define HEADS   8
#define HID     16
#define NCLS    10
#define CLSP    16    // padded cls row (64B aligned)
#define SCB     512   // scan block size
#define NPART   8     // XCD partitions for CSR scatter/count
#define PSZ     6250  // N_NODES / NPART
#define GROWS   64    // gemm rows per block (layer 0)
#define GR      16    // fused agg+gemm rows per block (layers 1-4); 50000/16=3125 exact

// el/er LAYOUT CONTRACT (layers 0-3): parity-permuted, head h stored at
// index (h&1)*4 + (h>>1). Lane parity b=q2>>1 then loads its 4 heads
// {b, b+2, b+4, b+6} as ONE aligned float4. Written by gemm0_count /
// fused_agg_gemm epilogues; consumed by agg_rows.

typedef unsigned short u16;
typedef __attribute__((ext_vector_type(8))) short bf16x8;
typedef __attribute__((ext_vector_type(4))) float f32x4;

__device__ __forceinline__ float bf2f(u16 u) {
    union { unsigned int i; float f; } c; c.i = ((unsigned int)u) << 16; return c.f;
}
__device__ __forceinline__ float bf2f_hi(unsigned int u) {
    union { unsigned int i; float f; } c; c.i = u & 0xffff0000u; return c.f;
}
__device__ __forceinline__ float bf2f_lo(unsigned int u) {
    union { unsigned int i; float f; } c; c.i = u << 16; return c.f;
}
__device__ __forceinline__ u16 f2bf(float f) {
    union { float f; unsigned int i; } c; c.f = f;
    unsigned int r = c.i + 0x7FFFu + ((c.i >> 16) & 1u);
    return (u16)(r >> 16);
}
__device__ __forceinline__ unsigned int pk2(float a, float b) {
    return (unsigned int)f2bf(a) | ((unsigned int)f2bf(b) << 16);
}
__device__ __forceinline__ float4 bf2f4(ushort4 u) {
    return make_float4(bf2f(u.x), bf2f(u.y), bf2f(u.z), bf2f(u.w));
}
__device__ __forceinline__ float4 ld4f(const u16* p)  { return bf2f4(*(const ushort4*)p); }
__device__ __forceinline__ void   st4(u16* p, float4 v) {
    ushort4 u; u.x = f2bf(v.x); u.y = f2bf(v.y); u.z = f2bf(v.z); u.w = f2bf(v.w);
    *(ushort4*)p = u;
}

// external-input decode (dtype resolved at runtime via flag)
__device__ __forceinline__ float ldin(const void* p, int i, bool isf32) {
    return isf32 ? ((const float*)p)[i] : bf2f(((const u16*)p)[i]);
}
__device__ __forceinline__ float4 ldin4(const void* p, int i4, bool isf32) {
    if (isf32) return ((const float4*)p)[i4];
    return bf2f4(((const ushort4*)p)[i4]);
}

// ---------------- dtype detection (W0 scan) + deg zeroing (merged grid) ----------------
__global__ void detect_and_zero(const u16* __restrict__ w, int n, int* __restrict__ flag,
                                int* __restrict__ deg) {
    if (blockIdx.x != 0) {
        int i = (blockIdx.x - 1) * 256 + threadIdx.x;
        if (i < N_NODES) deg[i] = 0;
        return;
    }
    __shared__ int s_huge, s_zero;
    if (threadIdx.x == 0) { s_huge = 0; s_zero = 0; }
    __syncthreads();
    int huge = 0, zero = 0;
    for (int i = threadIdx.x * 8; i < n; i += 256 * 8) {
        ushort4 a = *(const ushort4*)(w + i);
        ushort4 b = *(const ushort4*)(w + i + 4);
        u16 vals[8] = { a.x, a.y, a.z, a.w, b.x, b.y, b.z, b.w };
        #pragma unroll
        for (int k = 0; k < 8; k++) {
            float v = bf2f(vals[k]);
            if (fabsf(v) > 1e9f || v != v) huge++;
            if (vals[k] == 0) zero++;
        }
    }
    atomicAdd(&s_huge, huge);
    atomicAdd(&s_zero, zero);
    __syncthreads();
    if (threadIdx.x == 0)
        *flag = (s_huge > 0 || s_zero > n / 4) ? 1 : 0;
}

// ---------------- W transpose to bf16 (Wt[n][k]) for MFMA B-frags ----------------
__global__ void prep_wt(const void* __restrict__ W0, const void* __restrict__ W1,
                        const void* __restrict__ W2, const void* __restrict__ W3,
                        u16* __restrict__ Wt, const int* __restrict__ dflag) {
    const bool isf32 = (*dflag != 0);
    int l = blockIdx.y;
    const void* W = (l == 0) ? W0 : (l == 1) ? W1 : (l == 2) ? W2 : W3;
    int i = blockIdx.x * 256 + threadIdx.x;
    if (i >= FDIM * FDIM) return;
    int n = i >> 7, k = i & 127;
    Wt[l * FDIM * FDIM + n * FDIM + k] = f2bf(ldin(W, k * FDIM + n, isf32));
}

// ---------------- CSR build ----------------

__global__ void __launch_bounds__(SCB)
deg_bsum(const int* __restrict__ deg, int* __restrict__ bsum) {
    int i = blockIdx.x * SCB + threadIdx.x;
    int v = (i < N_NODES) ? deg[i] : 0;
    for (int off = 32; off; off >>= 1) v += __shfl_down(v, off, 64);
    __shared__ int wsum[SCB / 64];
    int wv = threadIdx.x >> 6, ln = threadIdx.x & 63;
    if (ln == 0) wsum[wv] = v;
    __syncthreads();
    if (threadIdx.x == 0) {
        int s = 0;
        #pragma unroll
        for (int k = 0; k < SCB / 64; k++) s += wsum[k];
        bsum[blockIdx.x] = s;
    }
}

// block scan of deg; each block sums bsum[0..blockIdx.x-1] itself (one wave)
__global__ void __launch_bounds__(SCB)
deg_scan2(const int* __restrict__ deg, const int* __restrict__ bsum,
          int* __restrict__ row_ptr, int* __restrict__ cursor) {
    __shared__ int sd[SCB];
    __shared__ int spfx;
    int tid = threadIdx.x;
    int i = blockIdx.x * SCB + tid;
    int v = (i < N_NODES) ? deg[i] : 0;
    sd[tid] = v;
    if (tid < 64) {
        int p = 0;
        if (tid < (int)blockIdx.x) p = bsum[tid];
        if (64 + tid < (int)blockIdx.x) p += bsum[64 + tid];
        for (int off = 32; off; off >>= 1) p += __shfl_down(p, off, 64);
        if (tid == 0) spfx = p;
    }
    __syncthreads();
    for (int off = 1; off < SCB; off <<= 1) {
        int t = (tid >= off) ? sd[tid - off] : 0;
        __syncthreads();
        sd[tid] += t;
        __syncthreads();
    }
    if (i < N_NODES) {
        int ex = sd[tid] - v + spfx;
        row_ptr[i] = ex;
        cursor[i] = ex;
    }
    if (blockIdx.x == 0 && tid == 0) row_ptr[N_NODES] = N_EDGES;
}

// XCD-partitioned scatter into u16 srcs (node ids < 65536).
__global__ void __launch_bounds__(256)
fill_csr_x(const int* __restrict__ src, const int* __restrict__ dst,
           int* __restrict__ cursor, u16* __restrict__ srcs, int blocksPerPart) {
    int part = blockIdx.x & (NPART - 1);
    int sub  = blockIdx.x >> 3;
    int lo = part * PSZ, hi = lo + PSZ;
    int stride = blocksPerPart * 256;
    for (int i = sub * 256 + threadIdx.x; i < N_EDGES; i += stride) {
        int d = __builtin_nontemporal_load(&dst[i]);
        if (d >= lo && d < hi) {
            int pos = atomicAdd(&cursor[d], 1);
            srcs[pos] = (u16)__builtin_nontemporal_load(&src[i]);
        }
    }
}

// ---------------- merged: layer-0 MFMA GEMM (+el/er)  ||  CSR degree count ----------------

__global__ void __launch_bounds__(256)
gemm0_count(const void* __restrict__ A, const u16* __restrict__ Wt,
            const void* __restrict__ alw, const void* __restrict__ arw,
            u16* __restrict__ C, float* __restrict__ el, float* __restrict__ er,
            const int* __restrict__ dflag,
            const int* __restrict__ dst, int* __restrict__ deg,
            int gemmBlocks, int blocksPerPart) {
    __shared__ __align__(16) char smem[GROWS * 132 * 4];  // Ct fp32 aliases As bf16
    if ((int)blockIdx.x >= gemmBlocks) {
        int b = blockIdx.x - gemmBlocks;
        int part = b & (NPART - 1);
        int sub  = b >> 3;
        int lo = part * PSZ, hi = lo + PSZ;
        int stride = blocksPerPart * 256;
        for (int i = sub * 256 + threadIdx.x; i < N_EDGES; i += stride) {
            int d = __builtin_nontemporal_load(&dst[i]);
            if (d >= lo && d < hi) atomicAdd(&deg[d], 1);
        }
        return;
    }
    u16   (*As)[136] = (u16(*)[136])smem;
    float (*Ct)[132] = (float(*)[132])smem;
    __shared__ u16 alv[128], arv[128];
    const bool isf32 = (*dflag != 0);
    int tid = threadIdx.x;
    if (tid < 128) {
        alv[tid] = f2bf(ldin(alw, tid, isf32));
        arv[tid] = f2bf(ldin(arw, tid, isf32));
    }
    int rowBase = blockIdx.x * GROWS;
    for (int t = tid; t < GROWS * 32; t += 256) {
        int r = t >> 5, q = t & 31;
        int n = rowBase + r;
        float4 v = make_float4(0.f, 0.f, 0.f, 0.f);
        if (n < N_NODES) v = ldin4(A, n * 32 + q, isf32);
        ushort4 u; u.x = f2bf(v.x); u.y = f2bf(v.y); u.z = f2bf(v.z); u.w = f2bf(v.w);
        *(ushort4*)&As[r][q * 4] = u;
    }
    int wv = tid >> 6, ln = tid & 63;
    int ln15 = ln & 15, quad = ln >> 4;
    bf16x8 bfr[2][4];
    #pragma unroll
    for (int c = 0; c < 2; c++)
        #pragma unroll
        for (int kk = 0; kk < 4; kk++)
            bfr[c][kk] = *(const bf16x8*)(Wt + (wv * 32 + c * 16 + ln15) * FDIM + kk * 32 + quad * 8);
    __syncthreads();
    f32x4 acc[4][2] = {};
    #pragma unroll
    for (int kk = 0; kk < 4; kk++) {
        #pragma unroll
        for (int rt = 0; rt < 4; rt++) {
            bf16x8 a = *(const bf16x8*)&As[rt * 16 + ln15][kk * 32 + quad * 8];
            acc[rt][0] = __builtin_amdgcn_mfma_f32_16x16x32_bf16(a, bfr[0][kk], acc[rt][0], 0, 0, 0);
            acc[rt][1] = __builtin_amdgcn_mfma_f32_16x16x32_bf16(a, bfr[1][kk], acc[rt][1], 0, 0, 0);
        }
    }
    __syncthreads();
    #pragma unroll
    for (int rt = 0; rt < 4; rt++)
        #pragma unroll
        for (int c = 0; c < 2; c++)
            #pragma unroll
            for (int p = 0; p < 4; p++)
                Ct[rt * 16 + quad * 4 + p][wv * 32 + c * 16 + ln15] = acc[rt][c][p];
    __syncthreads();
    int jc = (tid & 31) * 4, r0 = (tid >> 5) * 8;
    #pragma unroll
    for (int r = 0; r < 8; r++) {
        int n = rowBase + r0 + r;
        if (n < N_NODES)
            st4(C + (size_t)n * FDIM + jc, *(const float4*)&Ct[r0 + r][jc]);
    }
    int head = tid & 7;
    #pragma unroll
    for (int rr = 0; rr < 2; rr++) {
        int row = (tid >> 3) + rr * 32;
        int n2 = rowBase + row;
        if (n2 < N_NODES) {
            float sl = 0.f, sr = 0.f;
            #pragma unroll
            for (int k = 0; k < HID; k++) {
                float v = Ct[row][head * HID + k];
                sl += v * bf2f(alv[head * HID + k]);
                sr += v * bf2f(arv[head * HID + k]);
            }
            int ph = (head & 1) * 4 + (head >> 1);   // parity-permuted el/er slot
            el[n2 * HEADS + ph] = sl;
            er[n2 * HEADS + ph] = sr;
        }
    }
}

// ---------------- shared agg phase: 16 nodes/block -> ELU'd bf16 rows in LDS ----------------
// Wave layout: 4 nodes (sub=ln>>4), 4 edge slots (g=(ln>>2)&3), q2=ln&3 is the
// 16B OFFSET WITHIN each 64B cache line (not a 64B region): the 4 q2-lanes of a
// (sub,g) group read consecutive 16B of ONE line per instruction -> full line
// merge (16 line-transactions/instr vs 64 before). Lane's 32 cols span heads
// {b,b+2,b+4,b+6}, b=q2>>1; el/er parity-permuted layout gives them as one float4.
// Per-column accumulation order identical to previous versions (same g partition,
// same xor(4,8) tree) -> bit-identical results.

__device__ __forceinline__ void agg_rows(
    const u16* __restrict__ featP, const float* __restrict__ elP,
    const float* __restrict__ erP, const int* __restrict__ row_ptr,
    const u16* __restrict__ srcs, int rowBase, int tid, u16 (*As)[136]) {
    int wv = tid >> 6, ln = tid & 63;
    int sub = ln >> 4;            // node within wave (0..3)
    int g   = (ln >> 2) & 3;      // edge slot (0..3)
    int q2  = ln & 3;             // 16B offset within 64B line
    int b   = q2 >> 1;            // head parity
    int rp = 0;
    int k15 = ln & 15;
    {
        int ridx = rowBase + wv * 4 + k15;
        if (k15 <= 4) rp = row_ptr[ridx > N_NODES ? N_NODES : ridx];
    }
    int r = wv * 4 + sub;
    int n = rowBase + r;
    int beg = __shfl(rp, sub, 64);
    int end = __shfl(rp, sub + 1, 64);
    int nc = (n < N_NODES) ? n : 0;
    float4 erv = *(const float4*)&erP[nc * HEADS + b * 4];   // heads b,b+2,b+4,b+6
    float ss[4] = {};
    float acc[32] = {};
    // prefetch first src + el + feat row (OOB-safe)
    int idx0 = beg + g;
    int sN = srcs[(idx0 < end) ? idx0 : ((beg < end) ? beg : 0)];
    float4 elN_ = *(const float4*)&elP[sN * HEADS + b * 4];
    const u16* frN = featP + (unsigned)(sN * FDIM) + q2 * 8;
    uint4 p0 = *(const uint4*)frN;          // chunk 0: cols q2*8 .. +8
    uint4 p1 = *(const uint4*)(frN + 32);   // chunk 1: cols 32+q2*8 ..
    uint4 p2 = *(const uint4*)(frN + 64);   // chunk 2
    uint4 p3 = *(const uint4*)(frN + 96);   // chunk 3
    for (int i = beg; i < end; i += 4) {
        bool v = (i + g) < end;
        float4 elv = elN_;
        uint4 u0 = p0, u1 = p1, u2 = p2, u3 = p3;
        int nidx = i + 4 + g;
        sN = srcs[(nidx < end) ? nidx : beg];              // prefetch next src
        elN_ = *(const float4*)&elP[sN * HEADS + b * 4];   // prefetch next el
        const u16* fr2 = featP + (unsigned)(sN * FDIM) + q2 * 8;
        p0 = *(const uint4*)fr2;                           // prefetch next feat row
        p1 = *(const uint4*)(fr2 + 32);
        p2 = *(const uint4*)(fr2 + 64);
        p3 = *(const uint4*)(fr2 + 96);
        float e0 = elv.x + erv.x;   // head b     (chunk 0)
        float e1 = elv.y + erv.y;   // head b+2   (chunk 1)
        float e2 = elv.z + erv.z;   // head b+4   (chunk 2)
        float e3 = elv.w + erv.w;   // head b+6   (chunk 3)
        e0 = fmaxf(e0, 0.2f * e0);
        e1 = fmaxf(e1, 0.2f * e1);
        e2 = fmaxf(e2, 0.2f * e2);
        e3 = fmaxf(e3, 0.2f * e3);
        float x0 = v ? __expf(fminf(e0, 80.f)) : 0.f;
        float x1 = v ? __expf(fminf(e1, 80.f)) : 0.f;
        float x2 = v ? __expf(fminf(e2, 80.f)) : 0.f;
        float x3 = v ? __expf(fminf(e3, 80.f)) : 0.f;
        ss[0] += x0; ss[1] += x1; ss[2] += x2; ss[3] += x3;
        acc[0]  = fmaf(x0, bf2f_lo(u0.x), acc[0]);  acc[1]  = fmaf(x0, bf2f_hi(u0.x), acc[1]);
        acc[2]  = fmaf(x0, bf2f_lo(u0.y), acc[2]);  acc[3]  = fmaf(x0, bf2f_hi(u0.y), acc[3]);
        acc[4]  = fmaf(x0, bf2f_lo(u0.z), acc[4]);  acc[5]  = fmaf(x0, bf2f_hi(u0.z), acc[5]);
        acc[6]  = fmaf(x0, bf2f_lo(u0.w), acc[6]);  acc[7]  = fmaf(x0, bf2f_hi(u0.w), acc[7]);
        acc[8]  = fmaf(x1, bf2f_lo(u1.x), acc[8]);  acc[9]  = fmaf(x1, bf2f_hi(u1.x), acc[9]);
        acc[10] = fmaf(x1, bf2f_lo(u1.y), acc[10]); acc[11] = fmaf(x1, bf2f_hi(u1.y), acc[11]);
        acc[12] = fmaf(x1, bf2f_lo(u1.z), acc[12]); acc[13] = fmaf(x1, bf2f_hi(u1.z), acc[13]);
        acc[14] = fmaf(x1, bf2f_lo(u1.w), acc[14]); acc[15] = fmaf(x1, bf2f_hi(u1.w), acc[15]);
        acc[16] = fmaf(x2, bf2f_lo(u2.x), acc[16]); acc[17] = fmaf(x2, bf2f_hi(u2.x), acc[17]);
        acc[18] = fmaf(x2, bf2f_lo(u2.y), acc[18]); acc[19] = fmaf(x2, bf2f_hi(u2.y), acc[19]);
        acc[20] = fmaf(x2, bf2f_lo(u2.z), acc[20]); acc[21] = fmaf(x2, bf2f_hi(u2.z), acc[21]);
        acc[22] = fmaf(x2, bf2f_lo(u2.w), acc[22]); acc[23] = fmaf(x2, bf2f_hi(u2.w), acc[23]);
        acc[24] = fmaf(x3, bf2f_lo(u3.x), acc[24]); acc[25] = fmaf(x3, bf2f_hi(u3.x), acc[25]);
        acc[26] = fmaf(x3, bf2f_lo(u3.y), acc[26]); acc[27] = fmaf(x3, bf2f_hi(u3.y), acc[27]);
        acc[28] = fmaf(x3, bf2f_lo(u3.z), acc[28]); acc[29] = fmaf(x3, bf2f_hi(u3.z), acc[29]);
        acc[30] = fmaf(x3, bf2f_lo(u3.w), acc[30]); acc[31] = fmaf(x3, bf2f_hi(u3.w), acc[31]);
    }
    #pragma unroll
    for (int c = 0; c < 4; c++) {
        ss[c] += __shfl_xor(ss[c], 4, 64);
        ss[c] += __shfl_xor(ss[c], 8, 64);
    }
    #pragma unroll
    for (int k = 0; k < 32; k++) {
        acc[k] += __shfl_xor(acc[k], 4, 64);
        acc[k] += __shfl_xor(acc[k], 8, 64);
    }
    if (g == 0) {
        float inv[4];
        #pragma unroll
        for (int c = 0; c < 4; c++) inv[c] = (end > beg) ? 1.f / ss[c] : 0.f;
        float rr[32];
        #pragma unroll
        for (int k = 0; k < 32; k++) {
            float t = acc[k] * inv[k >> 3];
            rr[k] = (t > 0.f) ? t : (__expf(t) - 1.f);   // ELU
        }
        uint4 o0, o1, o2, o3;
        o0.x = pk2(rr[0],  rr[1]);  o0.y = pk2(rr[2],  rr[3]);
        o0.z = pk2(rr[4],  rr[5]);  o0.w = pk2(rr[6],  rr[7]);
        o1.x = pk2(rr[8],  rr[9]);  o1.y = pk2(rr[10], rr[11]);
        o1.z = pk2(rr[12], rr[13]); o1.w = pk2(rr[14], rr[15]);
        o2.x = pk2(rr[16], rr[17]); o2.y = pk2(rr[18], rr[19]);
        o2.z = pk2(rr[20], rr[21]); o2.w = pk2(rr[22], rr[23]);
        o3.x = pk2(rr[24], rr[25]); o3.y = pk2(rr[26], rr[27]);
        o3.z = pk2(rr[28], rr[29]); o3.w = pk2(rr[30], rr[31]);
        u16* dp = &As[r][q2 * 8];            // chunk c at col c*32 + q2*8
        *(uint4*)dp        = o0;
        *(uint4*)(dp + 32) = o1;
        *(uint4*)(dp + 64) = o2;
        *(uint4*)(dp + 96) = o3;
    }
}

// ---------------- fused agg (layer l-1, ELU) + MFMA GEMM (layer l) ----------------

__global__ void __launch_bounds__(256)
fused_agg_gemm(const u16* __restrict__ featP, const float* __restrict__ elP,
               const float* __restrict__ erP, const int* __restrict__ row_ptr,
               const u16* __restrict__ srcs, const u16* __restrict__ Wt,
               const void* __restrict__ alw, const void* __restrict__ arw,
               u16* __restrict__ featN, float* __restrict__ elN, float* __restrict__ erN,
               const int* __restrict__ dflag) {
    __shared__ __align__(16) char smem[GR * 132 * 4];   // Ct f32 (8448B) aliases As bf16 (4352B)
    u16   (*As)[136] = (u16(*)[136])smem;
    float (*Ct)[132] = (float(*)[132])smem;
    __shared__ u16 alv[128], arv[128];
    const bool isf32 = (*dflag != 0);
    int tid = threadIdx.x;
    if (tid < 128) {
        alv[tid] = f2bf(ldin(alw, tid, isf32));
        arv[tid] = f2bf(ldin(arw, tid, isf32));
    }
    int rowBase = blockIdx.x * GR;
    agg_rows(featP, elP, erP, row_ptr, srcs, rowBase, tid, As);
    int wv = tid >> 6, ln = tid & 63;
    int ln15 = ln & 15, quad = ln >> 4;
    bf16x8 bfr[2][4];
    #pragma unroll
    for (int c = 0; c < 2; c++)
        #pragma unroll
        for (int kk = 0; kk < 4; kk++)
            bfr[c][kk] = *(const bf16x8*)(Wt + (wv * 32 + c * 16 + ln15) * FDIM + kk * 32 + quad * 8);
    __syncthreads();
    // ---- GEMM phase (16 rows; wave wv -> cols wv*32..+31) ----
    f32x4 acc2[2] = {};
    #pragma unroll
    for (int kk = 0; kk < 4; kk++) {
        bf16x8 a = *(const bf16x8*)&As[ln15][kk * 32 + quad * 8];
        acc2[0] = __builtin_amdgcn_mfma_f32_16x16x32_bf16(a, bfr[0][kk], acc2[0], 0, 0, 0);
        acc2[1] = __builtin_amdgcn_mfma_f32_16x16x32_bf16(a, bfr[1][kk], acc2[1], 0, 0, 0);
    }
    __syncthreads();   // As reads done; smem becomes Ct
    #pragma unroll
    for (int c = 0; c < 2; c++)
        #pragma unroll
        for (int p = 0; p < 4; p++)
            Ct[quad * 4 + p][wv * 32 + c * 16 + ln15] = acc2[c][p];
    __syncthreads();
    // coalesced bf16 feat store: thread stores 2 rows x 4 cols
    int jc = (tid & 31) * 4, r0s = (tid >> 5) * 2;
    #pragma unroll
    for (int r2 = 0; r2 < 2; r2++) {
        int n = rowBase + r0s + r2;
        if (n < N_NODES)
            st4(featN + (size_t)n * FDIM + jc, *(const float4*)&Ct[r0s + r2][jc]);
    }
    // fused el/er: 16 rows x 8 heads = 128 items (parity-permuted slots)
    if (tid < 128) {
        int head = tid & 7, row2 = tid >> 3;
        int n2 = rowBase + row2;
        if (n2 < N_NODES) {
            float sl = 0.f, sr = 0.f;
            #pragma unroll
            for (int k = 0; k < HID; k++) {
                float v = Ct[row2][head * HID + k];
                sl += v * bf2f(alv[head * HID + k]);
                sr += v * bf2f(arv[head * HID + k]);
            }
            int ph = (head & 1) * 4 + (head >> 1);
            elN[n2 * HEADS + ph] = sl;
            erN[n2 * HEADS + ph] = sr;
        }
    }
}

// ---------------- fused agg (layer 3, ELU) + classifier GEMM (layer 4) + el/er ----------------

__global__ void __launch_bounds__(256)
fused_agg_cls(const u16* __restrict__ featP, const float* __restrict__ elP,
              const float* __restrict__ erP, const int* __restrict__ row_ptr,
              const u16* __restrict__ srcs, const void* __restrict__ W4,
              const void* __restrict__ alw, const void* __restrict__ arw,
              float* __restrict__ cls, float* __restrict__ elN, float* __restrict__ erN,
              const int* __restrict__ dflag) {
    __shared__ __align__(16) u16 As[GR][136];
    __shared__ float Wl[128][16];
    const bool isf32 = (*dflag != 0);
    int tid = threadIdx.x;
    for (int t = tid; t < 128 * 16; t += 256) {
        int k = t >> 4, c = t & 15;
        Wl[k][c] = (c < NCLS) ? ldin(W4, k * NCLS + c, isf32) : 0.f;
    }
    int rowBase = blockIdx.x * GR;
    agg_rows(featP, elP, erP, row_ptr, srcs, rowBase, tid, As);
    __syncthreads();
    // classifier: 16 rows x 16 cols, 1 output/thread
    int c = tid & 15;
    int row = tid >> 4;
    int n = rowBase + row;
    float alc = (c < NCLS) ? ldin(alw, c, isf32) : 0.f;
    float arc = (c < NCLS) ? ldin(arw, c, isf32) : 0.f;
    float acc = 0.f;
    #pragma unroll
    for (int qq = 0; qq < 32; qq++) {
        float4 v = ld4f(&As[row][qq * 4]);
        acc += v.x * Wl[qq * 4 + 0][c] + v.y * Wl[qq * 4 + 1][c] +
               v.z * Wl[qq * 4 + 2][c] + v.w * Wl[qq * 4 + 3][c];
    }
    if (n < N_NODES) cls[n * CLSP + c] = acc;
    float sl = acc * alc, sr = acc * arc;
    #pragma unroll
    for (int off = 8; off >= 1; off >>= 1) {
        sl += __shfl_xor(sl, off, 64);
        sr += __shfl_xor(sr, off, 64);
    }
    if (c == 0 && n < N_NODES) { elN[n] = sl; erN[n] = sr; }
}

// ---------------- final aggregation: 4 nodes per wave (16 lanes each) ----------------

__global__ void __launch_bounds__(256)
agg4(const float* __restrict__ feat, const float* __restrict__ el,
     const float* __restrict__ er, const int* __restrict__ row_ptr,
     const u16* __restrict__ srcs, void* __restrict__ out,
     const int* __restrict__ dflag) {
    const bool isf32 = (*dflag != 0);
    int wid = (blockIdx.x * 256 + threadIdx.x) >> 6;
    int lane = threadIdx.x & 63;
    int g = lane >> 4, t = lane & 15;
    int node = wid * 4 + g;
    bool vn = node < N_NODES;
    int nn = vn ? node : 0;
    int beg = row_ptr[nn];
    int end = vn ? row_ptr[nn + 1] : beg;
    float ern = er[nn];
    int deg = end - beg;
    int mx = deg;
    mx = max(mx, __shfl_xor(mx, 16, 64));
    mx = max(mx, __shfl_xor(mx, 32, 64));
    float ssA = 0.f, ssB = 0.f, aA = 0.f, aB = 0.f;
    int k = 0;
    for (; k + 1 < mx; k += 2) {
        int i0 = beg + k, i1 = i0 + 1;
        bool v0 = i0 < end, v1 = i1 < end;
        int s0 = srcs[v0 ? i0 : beg];
        int s1 = srcs[v1 ? i1 : beg];
        float e0 = el[s0] + ern;
        float e1 = el[s1] + ern;
        float f0 = feat[s0 * CLSP + t];
        float f1 = feat[s1 * CLSP + t];
        e0 = fmaxf(e0, 0.2f * e0); e1 = fmaxf(e1, 0.2f * e1);
        float x0 = v0 ? __expf(fminf(e0, 80.f)) : 0.f;
        float x1 = v1 ? __expf(fminf(e1, 80.f)) : 0.f;
        ssA += x0; ssB += x1;
        aA = fmaf(x0, f0, aA);
        aB = fmaf(x1, f1, aB);
    }
    if (k < mx) {
        int i0 = beg + k;
        bool v0 = i0 < end;
        int s0 = srcs[v0 ? i0 : beg];
        float e0 = el[s0] + ern;
        e0 = fmaxf(e0, 0.2f * e0);
        float x0 = v0 ? __expf(fminf(e0, 80.f)) : 0.f;
        ssA += x0;
        aA = fmaf(x0, feat[s0 * CLSP + t], aA);
    }
    float ss = ssA + ssB, a = aA + aB;
    if (vn && t < NCLS) {
        float r = (deg > 0) ? a / ss : 0.f;
        if (isf32) ((float*)out)[node * NCLS + t] = r;
        else       ((u16*)out)[node * NCLS + t] = f2bf(r);
    }
}

// ---------------- launch ----------------

extern "C" void kernel_launch(void* const* d_in, const int* in_sizes, int n_in,
                              void* d_out, int out_size, void* d_ws, size_t ws_size,
                              hipStream_t stream) {
    const void* h_in = d_in[0];
    const int* src   = (const int*)d_in[1];
    const int* dst   = (const int*)d_in[2];
    const void *W[5], *al[5], *ar[5];
    for (int l = 0; l < 5; l++) {
        W[l]  = d_in[3 + 3 * l];
        al[l] = d_in[4 + 3 * l];
        ar[l] = d_in[5 + 3 * l];
    }

    char* ws = (char*)d_ws;
    size_t off = 0;
    auto alloc = [&](size_t bytes) {
        void* p = ws + off;
        off = (off + bytes + 255) & ~(size_t)255;
        return p;
    };
    int* dflag   = (int*)alloc(4);
    u16* feat0   = (u16*)alloc((size_t)N_NODES * FDIM * sizeof(u16)); // ping
    u16* feat1   = (u16*)alloc((size_t)N_NODES * FDIM * sizeof(u16)); // pong
    u16* Wt      = (u16*)alloc(4ull * FDIM * FDIM * sizeof(u16));     // transposed bf16 weights
    float* el0   = (float*)alloc((size_t)N_NODES * HEADS * 4);
    float* er0   = (float*)alloc((size_t)N_NODES * HEADS * 4);
    float* el1   = (float*)alloc((size_t)N_NODES * HEADS * 4);
    float* er1   = (float*)alloc((size_t)N_NODES * HEADS * 4);
    float* cls   = (float*)alloc((size_t)N_NODES * CLSP * 4);
    int* deg     = (int*)alloc((size_t)N_NODES * 4);
    int* row_ptr = (int*)alloc((size_t)(N_NODES + 1) * 4);
    int* cursor  = (int*)alloc((size_t)N_NODES * 4);
    u16* srcs    = (u16*)alloc((size_t)N_EDGES * 2);
    int* bsum    = (int*)alloc(256 * 4);

    const int NB = (N_NODES + SCB - 1) / SCB;          // 98 scan blocks
    const int GB = (N_NODES + GROWS - 1) / GROWS;      // 782 gemm0 blocks
    const int CPP = 128;                               // count blocks per partition
    const int BPP = 256;                               // fill blocks per partition
    const int FB = N_NODES / GR;                       // 3125 fused blocks (exact)

    detect_and_zero<<<1 + (N_NODES + 255) / 256, 256, 0, stream>>>(
        (const u16*)W[0], FDIM * FDIM, dflag, deg);
    prep_wt<<<dim3((FDIM * FDIM + 255) / 256, 4), 256, 0, stream>>>(
        W[0], W[1], W[2], W[3], Wt, dflag);

    // layer-0 GEMM overlapped with CSR degree count (independent)
    gemm0_count<<<GB + NPART * CPP, 256, 0, stream>>>(
        h_in, Wt, al[0], ar[0], feat0, el0, er0, dflag, dst, deg, GB, CPP);

    deg_bsum<<<NB, SCB, 0, stream>>>(deg, bsum);
    deg_scan2<<<NB, SCB, 0, stream>>>(deg, bsum, row_ptr, cursor);
    fill_csr_x<<<NPART * BPP, 256, 0, stream>>>(src, dst, cursor, srcs, BPP);

    // layers 1-3: fused agg(l-1)+gemm(l), ping-pong buffers
    fused_agg_gemm<<<FB, 256, 0, stream>>>(
        feat0, el0, er0, row_ptr, srcs, Wt + 1 * FDIM * FDIM, al[1], ar[1],
        feat1, el1, er1, dflag);
    fused_agg_gemm<<<FB, 256, 0, stream>>>(
        feat1, el1, er1, row_ptr, srcs, Wt + 2 * FDIM * FDIM, al[2], ar[2],
        feat0, el0, er0, dflag);
    fused_agg_gemm<<<FB, 256, 0, stream>>>(
        feat0, el0, er0, row_ptr, srcs, Wt + 3 * FDIM * FDIM, al[3], ar[3],
        feat1, el1, er1, dflag);
    // layer-3 aggregation fused with classifier GEMM + layer-4 el/er
    fused_agg_cls<<<FB, 256, 0, stream>>>(
        feat1, el1, er1, row_ptr, srcs, W[4], al[4], ar[4], cls, el0, er0, dflag);
    agg4<<<(N_NODES / 16 + 1), 256, 0, stream>>>(cls, el0, er0, row_ptr, srcs, d_out, dflag);
}

// Round 8
// 391.375 us; speedup vs baseline: 1.3986x; 1.0233x over previous
//
#include <hip/hip_runtime.h>
#include <hip/hip_bf16.h>

#define N_NODES 50000
#define N_EDGES 800000
#define FDIM    128
#define HEADS   8
#define HID     16
#define NCLS    10
#define CLSP    16    // padded cls row (64B aligned)
#define SCB     512   // scan block size
#define NPART   8     // XCD partitions for CSR scatter/count
#define PSZ     6250  // N_NODES / NPART
#define GROWS   64    // gemm rows per block (layer 0)
#define GR      16    // fused agg+gemm rows per block (layers 1-4); 50000/16=3125 exact

// el/er LAYOUT CONTRACT (layers 0-3): parity-permuted, head h stored at
// index (h&1)*4 + (h>>1). Lane parity b=q2>>1 then loads its 4 heads
// {b, b+2, b+4, b+6} as ONE aligned float4.

typedef unsigned short u16;
typedef __attribute__((ext_vector_type(8))) short bf16x8;
typedef __attribute__((ext_vector_type(4))) float f32x4;

__device__ __forceinline__ float bf2f(u16 u) {
    union { unsigned int i; float f; } c; c.i = ((unsigned int)u) << 16; return c.f;
}
__device__ __forceinline__ float bf2f_hi(unsigned int u) {
    union { unsigned int i; float f; } c; c.i = u & 0xffff0000u; return c.f;
}
__device__ __forceinline__ float bf2f_lo(unsigned int u) {
    union { unsigned int i; float f; } c; c.i = u << 16; return c.f;
}
__device__ __forceinline__ u16 f2bf(float f) {
    union { float f; unsigned int i; } c; c.f = f;
    unsigned int r = c.i + 0x7FFFu + ((c.i >> 16) & 1u);
    return (u16)(r >> 16);
}
__device__ __forceinline__ unsigned int pk2(float a, float b) {
    return (unsigned int)f2bf(a) | ((unsigned int)f2bf(b) << 16);
}
__device__ __forceinline__ float4 bf2f4(ushort4 u) {
    return make_float4(bf2f(u.x), bf2f(u.y), bf2f(u.z), bf2f(u.w));
}
__device__ __forceinline__ float4 ld4f(const u16* p)  { return bf2f4(*(const ushort4*)p); }
__device__ __forceinline__ void   st4(u16* p, float4 v) {
    ushort4 u; u.x = f2bf(v.x); u.y = f2bf(v.y); u.z = f2bf(v.z); u.w = f2bf(v.w);
    *(ushort4*)p = u;
}

// external-input decode (dtype resolved at runtime via flag)
__device__ __forceinline__ float ldin(const void* p, int i, bool isf32) {
    return isf32 ? ((const float*)p)[i] : bf2f(((const u16*)p)[i]);
}
__device__ __forceinline__ float4 ldin4(const void* p, int i4, bool isf32) {
    if (isf32) return ((const float4*)p)[i4];
    return bf2f4(((const ushort4*)p)[i4]);
}

// ---------------- dtype detection (W0 scan) + deg zeroing (merged grid) ----------------
__global__ void detect_and_zero(const u16* __restrict__ w, int n, int* __restrict__ flag,
                                int* __restrict__ deg) {
    if (blockIdx.x != 0) {
        int i = (blockIdx.x - 1) * 256 + threadIdx.x;
        if (i < N_NODES) deg[i] = 0;
        return;
    }
    __shared__ int s_huge, s_zero;
    if (threadIdx.x == 0) { s_huge = 0; s_zero = 0; }
    __syncthreads();
    int huge = 0, zero = 0;
    for (int i = threadIdx.x * 8; i < n; i += 256 * 8) {
        ushort4 a = *(const ushort4*)(w + i);
        ushort4 b = *(const ushort4*)(w + i + 4);
        u16 vals[8] = { a.x, a.y, a.z, a.w, b.x, b.y, b.z, b.w };
        #pragma unroll
        for (int k = 0; k < 8; k++) {
            float v = bf2f(vals[k]);
            if (fabsf(v) > 1e9f || v != v) huge++;
            if (vals[k] == 0) zero++;
        }
    }
    atomicAdd(&s_huge, huge);
    atomicAdd(&s_zero, zero);
    __syncthreads();
    if (threadIdx.x == 0)
        *flag = (s_huge > 0 || s_zero > n / 4) ? 1 : 0;
}

// ---------------- W transpose to bf16 (Wt[n][k]) for MFMA B-frags ----------------
__global__ void prep_wt(const void* __restrict__ W0, const void* __restrict__ W1,
                        const void* __restrict__ W2, const void* __restrict__ W3,
                        u16* __restrict__ Wt, const int* __restrict__ dflag) {
    const bool isf32 = (*dflag != 0);
    int l = blockIdx.y;
    const void* W = (l == 0) ? W0 : (l == 1) ? W1 : (l == 2) ? W2 : W3;
    int i = blockIdx.x * 256 + threadIdx.x;
    if (i >= FDIM * FDIM) return;
    int n = i >> 7, k = i & 127;
    Wt[l * FDIM * FDIM + n * FDIM + k] = f2bf(ldin(W, k * FDIM + n, isf32));
}

// ---------------- CSR build ----------------

__global__ void __launch_bounds__(SCB)
deg_bsum(const int* __restrict__ deg, int* __restrict__ bsum) {
    int i = blockIdx.x * SCB + threadIdx.x;
    int v = (i < N_NODES) ? deg[i] : 0;
    for (int off = 32; off; off >>= 1) v += __shfl_down(v, off, 64);
    __shared__ int wsum[SCB / 64];
    int wv = threadIdx.x >> 6, ln = threadIdx.x & 63;
    if (ln == 0) wsum[wv] = v;
    __syncthreads();
    if (threadIdx.x == 0) {
        int s = 0;
        #pragma unroll
        for (int k = 0; k < SCB / 64; k++) s += wsum[k];
        bsum[blockIdx.x] = s;
    }
}

// block scan of deg; each block sums bsum[0..blockIdx.x-1] itself (one wave)
__global__ void __launch_bounds__(SCB)
deg_scan2(const int* __restrict__ deg, const int* __restrict__ bsum,
          int* __restrict__ row_ptr, int* __restrict__ cursor) {
    __shared__ int sd[SCB];
    __shared__ int spfx;
    int tid = threadIdx.x;
    int i = blockIdx.x * SCB + tid;
    int v = (i < N_NODES) ? deg[i] : 0;
    sd[tid] = v;
    if (tid < 64) {
        int p = 0;
        if (tid < (int)blockIdx.x) p = bsum[tid];
        if (64 + tid < (int)blockIdx.x) p += bsum[64 + tid];
        for (int off = 32; off; off >>= 1) p += __shfl_down(p, off, 64);
        if (tid == 0) spfx = p;
    }
    __syncthreads();
    for (int off = 1; off < SCB; off <<= 1) {
        int t = (tid >= off) ? sd[tid - off] : 0;
        __syncthreads();
        sd[tid] += t;
        __syncthreads();
    }
    if (i < N_NODES) {
        int ex = sd[tid] - v + spfx;
        row_ptr[i] = ex;
        cursor[i] = ex;
    }
    if (blockIdx.x == 0 && tid == 0) row_ptr[N_NODES] = N_EDGES;
}

// XCD-partitioned scatter into u16 srcs (node ids < 65536). int4-vectorized,
// L3-cached reads (no NT): dst+src fetched from HBM once, re-read from L3 7x.
__global__ void __launch_bounds__(256)
fill_csr_x(const int* __restrict__ src, const int* __restrict__ dst,
           int* __restrict__ cursor, u16* __restrict__ srcs, int blocksPerPart) {
    int part = blockIdx.x & (NPART - 1);
    int sub  = blockIdx.x >> 3;
    int lo = part * PSZ, hi = lo + PSZ;
    int stride = blocksPerPart * 256;
    const int4* dst4 = (const int4*)dst;
    const int4* src4 = (const int4*)src;
    const int nv = N_EDGES / 4;
    for (int i = sub * 256 + threadIdx.x; i < nv; i += stride) {
        int4 d = dst4[i];
        int4 s = src4[i];
        if (d.x >= lo && d.x < hi) { int p = atomicAdd(&cursor[d.x], 1); srcs[p] = (u16)s.x; }
        if (d.y >= lo && d.y < hi) { int p = atomicAdd(&cursor[d.y], 1); srcs[p] = (u16)s.y; }
        if (d.z >= lo && d.z < hi) { int p = atomicAdd(&cursor[d.z], 1); srcs[p] = (u16)s.z; }
        if (d.w >= lo && d.w < hi) { int p = atomicAdd(&cursor[d.w], 1); srcs[p] = (u16)s.w; }
    }
}

// ---------------- merged: layer-0 MFMA GEMM (+el/er)  ||  CSR degree count ----------------

__global__ void __launch_bounds__(256)
gemm0_count(const void* __restrict__ A, const u16* __restrict__ Wt,
            const void* __restrict__ alw, const void* __restrict__ arw,
            u16* __restrict__ C, float* __restrict__ el, float* __restrict__ er,
            const int* __restrict__ dflag,
            const int* __restrict__ dst, int* __restrict__ deg,
            int gemmBlocks, int blocksPerPart) {
    __shared__ __align__(16) char smem[GROWS * 132 * 4];  // Ct fp32 aliases As bf16
    if ((int)blockIdx.x >= gemmBlocks) {
        // ---- degree count branch: int4 loads, L3-cached (no NT) ----
        int b = blockIdx.x - gemmBlocks;
        int part = b & (NPART - 1);
        int sub  = b >> 3;
        int lo = part * PSZ, hi = lo + PSZ;
        int stride = blocksPerPart * 256;
        const int4* dst4 = (const int4*)dst;
        const int nv = N_EDGES / 4;
        for (int i = sub * 256 + threadIdx.x; i < nv; i += stride) {
            int4 d = dst4[i];
            if (d.x >= lo && d.x < hi) atomicAdd(&deg[d.x], 1);
            if (d.y >= lo && d.y < hi) atomicAdd(&deg[d.y], 1);
            if (d.z >= lo && d.z < hi) atomicAdd(&deg[d.z], 1);
            if (d.w >= lo && d.w < hi) atomicAdd(&deg[d.w], 1);
        }
        return;
    }
    u16   (*As)[136] = (u16(*)[136])smem;
    float (*Ct)[132] = (float(*)[132])smem;
    __shared__ u16 alv[128], arv[128];
    const bool isf32 = (*dflag != 0);
    int tid = threadIdx.x;
    if (tid < 128) {
        alv[tid] = f2bf(ldin(alw, tid, isf32));
        arv[tid] = f2bf(ldin(arw, tid, isf32));
    }
    int rowBase = blockIdx.x * GROWS;
    for (int t = tid; t < GROWS * 32; t += 256) {
        int r = t >> 5, q = t & 31;
        int n = rowBase + r;
        float4 v = make_float4(0.f, 0.f, 0.f, 0.f);
        if (n < N_NODES) v = ldin4(A, n * 32 + q, isf32);
        ushort4 u; u.x = f2bf(v.x); u.y = f2bf(v.y); u.z = f2bf(v.z); u.w = f2bf(v.w);
        *(ushort4*)&As[r][q * 4] = u;
    }
    int wv = tid >> 6, ln = tid & 63;
    int ln15 = ln & 15, quad = ln >> 4;
    bf16x8 bfr[2][4];
    #pragma unroll
    for (int c = 0; c < 2; c++)
        #pragma unroll
        for (int kk = 0; kk < 4; kk++)
            bfr[c][kk] = *(const bf16x8*)(Wt + (wv * 32 + c * 16 + ln15) * FDIM + kk * 32 + quad * 8);
    __syncthreads();
    f32x4 acc[4][2] = {};
    #pragma unroll
    for (int kk = 0; kk < 4; kk++) {
        #pragma unroll
        for (int rt = 0; rt < 4; rt++) {
            bf16x8 a = *(const bf16x8*)&As[rt * 16 + ln15][kk * 32 + quad * 8];
            acc[rt][0] = __builtin_amdgcn_mfma_f32_16x16x32_bf16(a, bfr[0][kk], acc[rt][0], 0, 0, 0);
            acc[rt][1] = __builtin_amdgcn_mfma_f32_16x16x32_bf16(a, bfr[1][kk], acc[rt][1], 0, 0, 0);
        }
    }
    __syncthreads();
    #pragma unroll
    for (int rt = 0; rt < 4; rt++)
        #pragma unroll
        for (int c = 0; c < 2; c++)
            #pragma unroll
            for (int p = 0; p < 4; p++)
                Ct[rt * 16 + quad * 4 + p][wv * 32 + c * 16 + ln15] = acc[rt][c][p];
    __syncthreads();
    int jc = (tid & 31) * 4, r0 = (tid >> 5) * 8;
    #pragma unroll
    for (int r = 0; r < 8; r++) {
        int n = rowBase + r0 + r;
        if (n < N_NODES)
            st4(C + (size_t)n * FDIM + jc, *(const float4*)&Ct[r0 + r][jc]);
    }
    int head = tid & 7;
    #pragma unroll
    for (int rr = 0; rr < 2; rr++) {
        int row = (tid >> 3) + rr * 32;
        int n2 = rowBase + row;
        if (n2 < N_NODES) {
            float sl = 0.f, sr = 0.f;
            #pragma unroll
            for (int k = 0; k < HID; k++) {
                float v = Ct[row][head * HID + k];
                sl += v * bf2f(alv[head * HID + k]);
                sr += v * bf2f(arv[head * HID + k]);
            }
            int ph = (head & 1) * 4 + (head >> 1);   // parity-permuted el/er slot
            el[n2 * HEADS + ph] = sl;
            er[n2 * HEADS + ph] = sr;
        }
    }
}

// ---------------- shared agg phase: 16 nodes/block -> ELU'd bf16 rows in LDS ----------------
// Wave layout: 4 nodes (sub=ln>>4), 4 edge slots (g=(ln>>2)&3), q2=ln&3 is the
// 16B OFFSET WITHIN each 64B cache line: the 4 q2-lanes of a (sub,g) group read
// consecutive 16B of ONE line per instruction -> full line merge. Lane's 32 cols
// span heads {b,b+2,b+4,b+6}, b=q2>>1; parity-permuted el/er gives one float4.

__device__ __forceinline__ void agg_rows(
    const u16* __restrict__ featP, const float* __restrict__ elP,
    const float* __restrict__ erP, const int* __restrict__ row_ptr,
    const u16* __restrict__ srcs, int rowBase, int tid, u16 (*As)[136]) {
    int wv = tid >> 6, ln = tid & 63;
    int sub = ln >> 4;            // node within wave (0..3)
    int g   = (ln >> 2) & 3;      // edge slot (0..3)
    int q2  = ln & 3;             // 16B offset within 64B line
    int b   = q2 >> 1;            // head parity
    int rp = 0;
    int k15 = ln & 15;
    {
        int ridx = rowBase + wv * 4 + k15;
        if (k15 <= 4) rp = row_ptr[ridx > N_NODES ? N_NODES : ridx];
    }
    int r = wv * 4 + sub;
    int n = rowBase + r;
    int beg = __shfl(rp, sub, 64);
    int end = __shfl(rp, sub + 1, 64);
    int nc = (n < N_NODES) ? n : 0;
    float4 erv = *(const float4*)&erP[nc * HEADS + b * 4];   // heads b,b+2,b+4,b+6
    float ss[4] = {};
    float acc[32] = {};
    // prefetch first src + el + feat row (OOB-safe)
    int idx0 = beg + g;
    int sN = srcs[(idx0 < end) ? idx0 : ((beg < end) ? beg : 0)];
    float4 elN_ = *(const float4*)&elP[sN * HEADS + b * 4];
    const u16* frN = featP + (unsigned)(sN * FDIM) + q2 * 8;
    uint4 p0 = *(const uint4*)frN;          // chunk 0: cols q2*8 .. +8
    uint4 p1 = *(const uint4*)(frN + 32);   // chunk 1
    uint4 p2 = *(const uint4*)(frN + 64);   // chunk 2
    uint4 p3 = *(const uint4*)(frN + 96);   // chunk 3
    for (int i = beg; i < end; i += 4) {
        bool v = (i + g) < end;
        float4 elv = elN_;
        uint4 u0 = p0, u1 = p1, u2 = p2, u3 = p3;
        int nidx = i + 4 + g;
        sN = srcs[(nidx < end) ? nidx : beg];              // prefetch next src
        elN_ = *(const float4*)&elP[sN * HEADS + b * 4];   // prefetch next el
        const u16* fr2 = featP + (unsigned)(sN * FDIM) + q2 * 8;
        p0 = *(const uint4*)fr2;                           // prefetch next feat row
        p1 = *(const uint4*)(fr2 + 32);
        p2 = *(const uint4*)(fr2 + 64);
        p3 = *(const uint4*)(fr2 + 96);
        float e0 = elv.x + erv.x;   // head b     (chunk 0)
        float e1 = elv.y + erv.y;   // head b+2   (chunk 1)
        float e2 = elv.z + erv.z;   // head b+4   (chunk 2)
        float e3 = elv.w + erv.w;   // head b+6   (chunk 3)
        e0 = fmaxf(e0, 0.2f * e0);
        e1 = fmaxf(e1, 0.2f * e1);
        e2 = fmaxf(e2, 0.2f * e2);
        e3 = fmaxf(e3, 0.2f * e3);
        float x0 = v ? __expf(fminf(e0, 80.f)) : 0.f;
        float x1 = v ? __expf(fminf(e1, 80.f)) : 0.f;
        float x2 = v ? __expf(fminf(e2, 80.f)) : 0.f;
        float x3 = v ? __expf(fminf(e3, 80.f)) : 0.f;
        ss[0] += x0; ss[1] += x1; ss[2] += x2; ss[3] += x3;
        acc[0]  = fmaf(x0, bf2f_lo(u0.x), acc[0]);  acc[1]  = fmaf(x0, bf2f_hi(u0.x), acc[1]);
        acc[2]  = fmaf(x0, bf2f_lo(u0.y), acc[2]);  acc[3]  = fmaf(x0, bf2f_hi(u0.y), acc[3]);
        acc[4]  = fmaf(x0, bf2f_lo(u0.z), acc[4]);  acc[5]  = fmaf(x0, bf2f_hi(u0.z), acc[5]);
        acc[6]  = fmaf(x0, bf2f_lo(u0.w), acc[6]);  acc[7]  = fmaf(x0, bf2f_hi(u0.w), acc[7]);
        acc[8]  = fmaf(x1, bf2f_lo(u1.x), acc[8]);  acc[9]  = fmaf(x1, bf2f_hi(u1.x), acc[9]);
        acc[10] = fmaf(x1, bf2f_lo(u1.y), acc[10]); acc[11] = fmaf(x1, bf2f_hi(u1.y), acc[11]);
        acc[12] = fmaf(x1, bf2f_lo(u1.z), acc[12]); acc[13] = fmaf(x1, bf2f_hi(u1.z), acc[13]);
        acc[14] = fmaf(x1, bf2f_lo(u1.w), acc[14]); acc[15] = fmaf(x1, bf2f_hi(u1.w), acc[15]);
        acc[16] = fmaf(x2, bf2f_lo(u2.x), acc[16]); acc[17] = fmaf(x2, bf2f_hi(u2.x), acc[17]);
        acc[18] = fmaf(x2, bf2f_lo(u2.y), acc[18]); acc[19] = fmaf(x2, bf2f_hi(u2.y), acc[19]);
        acc[20] = fmaf(x2, bf2f_lo(u2.z), acc[20]); acc[21] = fmaf(x2, bf2f_hi(u2.z), acc[21]);
        acc[22] = fmaf(x2, bf2f_lo(u2.w), acc[22]); acc[23] = fmaf(x2, bf2f_hi(u2.w), acc[23]);
        acc[24] = fmaf(x3, bf2f_lo(u3.x), acc[24]); acc[25] = fmaf(x3, bf2f_hi(u3.x), acc[25]);
        acc[26] = fmaf(x3, bf2f_lo(u3.y), acc[26]); acc[27] = fmaf(x3, bf2f_hi(u3.y), acc[27]);
        acc[28] = fmaf(x3, bf2f_lo(u3.z), acc[28]); acc[29] = fmaf(x3, bf2f_hi(u3.z), acc[29]);
        acc[30] = fmaf(x3, bf2f_lo(u3.w), acc[30]); acc[31] = fmaf(x3, bf2f_hi(u3.w), acc[31]);
    }
    #pragma unroll
    for (int c = 0; c < 4; c++) {
        ss[c] += __shfl_xor(ss[c], 4, 64);
        ss[c] += __shfl_xor(ss[c], 8, 64);
    }
    #pragma unroll
    for (int k = 0; k < 32; k++) {
        acc[k] += __shfl_xor(acc[k], 4, 64);
        acc[k] += __shfl_xor(acc[k], 8, 64);
    }
    if (g == 0) {
        float inv[4];
        #pragma unroll
        for (int c = 0; c < 4; c++) inv[c] = (end > beg) ? 1.f / ss[c] : 0.f;
        float rr[32];
        #pragma unroll
        for (int k = 0; k < 32; k++) {
            float t = acc[k] * inv[k >> 3];
            rr[k] = (t > 0.f) ? t : (__expf(t) - 1.f);   // ELU
        }
        uint4 o0, o1, o2, o3;
        o0.x = pk2(rr[0],  rr[1]);  o0.y = pk2(rr[2],  rr[3]);
        o0.z = pk2(rr[4],  rr[5]);  o0.w = pk2(rr[6],  rr[7]);
        o1.x = pk2(rr[8],  rr[9]);  o1.y = pk2(rr[10], rr[11]);
        o1.z = pk2(rr[12], rr[13]); o1.w = pk2(rr[14], rr[15]);
        o2.x = pk2(rr[16], rr[17]); o2.y = pk2(rr[18], rr[19]);
        o2.z = pk2(rr[20], rr[21]); o2.w = pk2(rr[22], rr[23]);
        o3.x = pk2(rr[24], rr[25]); o3.y = pk2(rr[26], rr[27]);
        o3.z = pk2(rr[28], rr[29]); o3.w = pk2(rr[30], rr[31]);
        u16* dp = &As[r][q2 * 8];            // chunk c at col c*32 + q2*8
        *(uint4*)dp        = o0;
        *(uint4*)(dp + 32) = o1;
        *(uint4*)(dp + 64) = o2;
        *(uint4*)(dp + 96) = o3;
    }
}

// ---------------- fused agg (layer l-1, ELU) + MFMA GEMM (layer l) ----------------

__global__ void __launch_bounds__(256)
fused_agg_gemm(const u16* __restrict__ featP, const float* __restrict__ elP,
               const float* __restrict__ erP, const int* __restrict__ row_ptr,
               const u16* __restrict__ srcs, const u16* __restrict__ Wt,
               const void* __restrict__ alw, const void* __restrict__ arw,
               u16* __restrict__ featN, float* __restrict__ elN, float* __restrict__ erN,
               const int* __restrict__ dflag) {
    __shared__ __align__(16) char smem[GR * 132 * 4];   // Ct f32 (8448B) aliases As bf16 (4352B)
    u16   (*As)[136] = (u16(*)[136])smem;
    float (*Ct)[132] = (float(*)[132])smem;
    __shared__ u16 alv[128], arv[128];
    const bool isf32 = (*dflag != 0);
    int tid = threadIdx.x;
    if (tid < 128) {
        alv[tid] = f2bf(ldin(alw, tid, isf32));
        arv[tid] = f2bf(ldin(arw, tid, isf32));
    }
    int rowBase = blockIdx.x * GR;
    agg_rows(featP, elP, erP, row_ptr, srcs, rowBase, tid, As);
    int wv = tid >> 6, ln = tid & 63;
    int ln15 = ln & 15, quad = ln >> 4;
    bf16x8 bfr[2][4];
    #pragma unroll
    for (int c = 0; c < 2; c++)
        #pragma unroll
        for (int kk = 0; kk < 4; kk++)
            bfr[c][kk] = *(const bf16x8*)(Wt + (wv * 32 + c * 16 + ln15) * FDIM + kk * 32 + quad * 8);
    __syncthreads();
    // ---- GEMM phase (16 rows; wave wv -> cols wv*32..+31) ----
    f32x4 acc2[2] = {};
    #pragma unroll
    for (int kk = 0; kk < 4; kk++) {
        bf16x8 a = *(const bf16x8*)&As[ln15][kk * 32 + quad * 8];
        acc2[0] = __builtin_amdgcn_mfma_f32_16x16x32_bf16(a, bfr[0][kk], acc2[0], 0, 0, 0);
        acc2[1] = __builtin_amdgcn_mfma_f32_16x16x32_bf16(a, bfr[1][kk], acc2[1], 0, 0, 0);
    }
    __syncthreads();   // As reads done; smem becomes Ct
    #pragma unroll
    for (int c = 0; c < 2; c++)
        #pragma unroll
        for (int p = 0; p < 4; p++)
            Ct[quad * 4 + p][wv * 32 + c * 16 + ln15] = acc2[c][p];
    __syncthreads();
    // coalesced bf16 feat store: thread stores 2 rows x 4 cols
    int jc = (tid & 31) * 4, r0s = (tid >> 5) * 2;
    #pragma unroll
    for (int r2 = 0; r2 < 2; r2++) {
        int n = rowBase + r0s + r2;
        if (n < N_NODES)
            st4(featN + (size_t)n * FDIM + jc, *(const float4*)&Ct[r0s + r2][jc]);
    }
    // fused el/er: 16 rows x 8 heads = 128 items (parity-permuted slots)
    if (tid < 128) {
        int head = tid & 7, row2 = tid >> 3;
        int n2 = rowBase + row2;
        if (n2 < N_NODES) {
            float sl = 0.f, sr = 0.f;
            #pragma unroll
            for (int k = 0; k < HID; k++) {
                float v = Ct[row2][head * HID + k];
                sl += v * bf2f(alv[head * HID + k]);
                sr += v * bf2f(arv[head * HID + k]);
            }
            int ph = (head & 1) * 4 + (head >> 1);
            elN[n2 * HEADS + ph] = sl;
            erN[n2 * HEADS + ph] = sr;
        }
    }
}

// ---------------- fused agg (layer 3, ELU) + classifier GEMM (layer 4) + el/er ----------------

__global__ void __launch_bounds__(256)
fused_agg_cls(const u16* __restrict__ featP, const float* __restrict__ elP,
              const float* __restrict__ erP, const int* __restrict__ row_ptr,
              const u16* __restrict__ srcs, const void* __restrict__ W4,
              const void* __restrict__ alw, const void* __restrict__ arw,
              float* __restrict__ cls, float* __restrict__ elN, float* __restrict__ erN,
              const int* __restrict__ dflag) {
    __shared__ __align__(16) u16 As[GR][136];
    __shared__ float Wl[128][16];
    const bool isf32 = (*dflag != 0);
    int tid = threadIdx.x;
    for (int t = tid; t < 128 * 16; t += 256) {
        int k = t >> 4, c = t & 15;
        Wl[k][c] = (c < NCLS) ? ldin(W4, k * NCLS + c, isf32) : 0.f;
    }
    int rowBase = blockIdx.x * GR;
    agg_rows(featP, elP, erP, row_ptr, srcs, rowBase, tid, As);
    __syncthreads();
    // classifier: 16 rows x 16 cols, 1 output/thread
    int c = tid & 15;
    int row = tid >> 4;
    int n = rowBase + row;
    float alc = (c < NCLS) ? ldin(alw, c, isf32) : 0.f;
    float arc = (c < NCLS) ? ldin(arw, c, isf32) : 0.f;
    float acc = 0.f;
    #pragma unroll
    for (int qq = 0; qq < 32; qq++) {
        float4 v = ld4f(&As[row][qq * 4]);
        acc += v.x * Wl[qq * 4 + 0][c] + v.y * Wl[qq * 4 + 1][c] +
               v.z * Wl[qq * 4 + 2][c] + v.w * Wl[qq * 4 + 3][c];
    }
    if (n < N_NODES) cls[n * CLSP + c] = acc;
    float sl = acc * alc, sr = acc * arc;
    #pragma unroll
    for (int off = 8; off >= 1; off >>= 1) {
        sl += __shfl_xor(sl, off, 64);
        sr += __shfl_xor(sr, off, 64);
    }
    if (c == 0 && n < N_NODES) { elN[n] = sl; erN[n] = sr; }
}

// ---------------- final aggregation: 4 nodes per wave (16 lanes each) ----------------

__global__ void __launch_bounds__(256)
agg4(const float* __restrict__ feat, const float* __restrict__ el,
     const float* __restrict__ er, const int* __restrict__ row_ptr,
     const u16* __restrict__ srcs, void* __restrict__ out,
     const int* __restrict__ dflag) {
    const bool isf32 = (*dflag != 0);
    int wid = (blockIdx.x * 256 + threadIdx.x) >> 6;
    int lane = threadIdx.x & 63;
    int g = lane >> 4, t = lane & 15;
    int node = wid * 4 + g;
    bool vn = node < N_NODES;
    int nn = vn ? node : 0;
    int beg = row_ptr[nn];
    int end = vn ? row_ptr[nn + 1] : beg;
    float ern = er[nn];
    int deg = end - beg;
    int mx = deg;
    mx = max(mx, __shfl_xor(mx, 16, 64));
    mx = max(mx, __shfl_xor(mx, 32, 64));
    float ssA = 0.f, ssB = 0.f, aA = 0.f, aB = 0.f;
    int k = 0;
    for (; k + 1 < mx; k += 2) {
        int i0 = beg + k, i1 = i0 + 1;
        bool v0 = i0 < end, v1 = i1 < end;
        int s0 = srcs[v0 ? i0 : beg];
        int s1 = srcs[v1 ? i1 : beg];
        float e0 = el[s0] + ern;
        float e1 = el[s1] + ern;
        float f0 = feat[s0 * CLSP + t];
        float f1 = feat[s1 * CLSP + t];
        e0 = fmaxf(e0, 0.2f * e0); e1 = fmaxf(e1, 0.2f * e1);
        float x0 = v0 ? __expf(fminf(e0, 80.f)) : 0.f;
        float x1 = v1 ? __expf(fminf(e1, 80.f)) : 0.f;
        ssA += x0; ssB += x1;
        aA = fmaf(x0, f0, aA);
        aB = fmaf(x1, f1, aB);
    }
    if (k < mx) {
        int i0 = beg + k;
        bool v0 = i0 < end;
        int s0 = srcs[v0 ? i0 : beg];
        float e0 = el[s0] + ern;
        e0 = fmaxf(e0, 0.2f * e0);
        float x0 = v0 ? __expf(fminf(e0, 80.f)) : 0.f;
        ssA += x0;
        aA = fmaf(x0, feat[s0 * CLSP + t], aA);
    }
    float ss = ssA + ssB, a = aA + aB;
    if (vn && t < NCLS) {
        float r = (deg > 0) ? a / ss : 0.f;
        if (isf32) ((float*)out)[node * NCLS + t] = r;
        else       ((u16*)out)[node * NCLS + t] = f2bf(r);
    }
}

// ---------------- launch ----------------

extern "C" void kernel_launch(void* const* d_in, const int* in_sizes, int n_in,
                              void* d_out, int out_size, void* d_ws, size_t ws_size,
                              hipStream_t stream) {
    const void* h_in = d_in[0];
    const int* src   = (const int*)d_in[1];
    const int* dst   = (const int*)d_in[2];
    const void *W[5], *al[5], *ar[5];
    for (int l = 0; l < 5; l++) {
        W[l]  = d_in[3 + 3 * l];
        al[l] = d_in[4 + 3 * l];
        ar[l] = d_in[5 + 3 * l];
    }

    char* ws = (char*)d_ws;
    size_t off = 0;
    auto alloc = [&](size_t bytes) {
        void* p = ws + off;
        off = (off + bytes + 255) & ~(size_t)255;
        return p;
    };
    int* dflag   = (int*)alloc(4);
    u16* feat0   = (u16*)alloc((size_t)N_NODES * FDIM * sizeof(u16)); // ping
    u16* feat1   = (u16*)alloc((size_t)N_NODES * FDIM * sizeof(u16)); // pong
    u16* Wt      = (u16*)alloc(4ull * FDIM * FDIM * sizeof(u16));     // transposed bf16 weights
    float* el0   = (float*)alloc((size_t)N_NODES * HEADS * 4);
    float* er0   = (float*)alloc((size_t)N_NODES * HEADS * 4);
    float* el1   = (float*)alloc((size_t)N_NODES * HEADS * 4);
    float* er1   = (float*)alloc((size_t)N_NODES * HEADS * 4);
    float* cls   = (float*)alloc((size_t)N_NODES * CLSP * 4);
    int* deg     = (int*)alloc((size_t)N_NODES * 4);
    int* row_ptr = (int*)alloc((size_t)(N_NODES + 1) * 4);
    int* cursor  = (int*)alloc((size_t)N_NODES * 4);
    u16* srcs    = (u16*)alloc((size_t)N_EDGES * 2);
    int* bsum    = (int*)alloc(256 * 4);

    const int NB = (N_NODES + SCB - 1) / SCB;          // 98 scan blocks
    const int GB = (N_NODES + GROWS - 1) / GROWS;      // 782 gemm0 blocks
    const int CPP = 64;                                // count blocks per partition (int4: 512 blocks, ~12 iters)
    const int BPP = 128;                               // fill blocks per partition (int4: 1024 blocks)
    const int FB = N_NODES / GR;                       // 3125 fused blocks (exact)

    detect_and_zero<<<1 + (N_NODES + 255) / 256, 256, 0, stream>>>(
        (const u16*)W[0], FDIM * FDIM, dflag, deg);
    prep_wt<<<dim3((FDIM * FDIM + 255) / 256, 4), 256, 0, stream>>>(
        W[0], W[1], W[2], W[3], Wt, dflag);

    // layer-0 GEMM overlapped with CSR degree count (independent)
    gemm0_count<<<GB + NPART * CPP, 256, 0, stream>>>(
        h_in, Wt, al[0], ar[0], feat0, el0, er0, dflag, dst, deg, GB, CPP);

    deg_bsum<<<NB, SCB, 0, stream>>>(deg, bsum);
    deg_scan2<<<NB, SCB, 0, stream>>>(deg, bsum, row_ptr, cursor);
    fill_csr_x<<<NPART * BPP, 256, 0, stream>>>(src, dst, cursor, srcs, BPP);

    // layers 1-3: fused agg(l-1)+gemm(l), ping-pong buffers
    fused_agg_gemm<<<FB, 256, 0, stream>>>(
        feat0, el0, er0, row_ptr, srcs, Wt + 1 * FDIM * FDIM, al[1], ar[1],
        feat1, el1, er1, dflag);
    fused_agg_gemm<<<FB, 256, 0, stream>>>(
        feat1, el1, er1, row_ptr, srcs, Wt + 2 * FDIM * FDIM, al[2], ar[2],
        feat0, el0, er0, dflag);
    fused_agg_gemm<<<FB, 256, 0, stream>>>(
        feat0, el0, er0, row_ptr, srcs, Wt + 3 * FDIM * FDIM, al[3], ar[3],
        feat1, el1, er1, dflag);
    // layer-3 aggregation fused with classifier GEMM + layer-4 el/er
    fused_agg_cls<<<FB, 256, 0, stream>>>(
        feat1, el1, er1, row_ptr, srcs, W[4], al[4], ar[4], cls, el0, er0, dflag);
    agg4<<<(N_NODES / 16 + 1), 256, 0, stream>>>(cls, el0, er0, row_ptr, srcs, d_out, dflag);
}